// Round 7
// baseline (407.322 us; speedup 1.0000x reference)
//
#include <hip/hip_runtime.h>
#include <stdint.h>

#define NN 50000
#define NE 800000
#define NR (NN*8)            // (node, relation) segments
#define SCAN_BS 512
#define NB2 782              // ceil(NR/512)
#define INV_N (1.0f/50000.0f)
#define BN_EPS 1e-5f

typedef unsigned short ushort_t;
typedef unsigned char uchar_t;
typedef short bf16x8 __attribute__((ext_vector_type(8)));   // 8 bf16 (4 VGPRs)
typedef float f32x4 __attribute__((ext_vector_type(4)));
typedef float f32x2 __attribute__((ext_vector_type(2)));

__device__ __forceinline__ ushort_t f2bf(float f){
    unsigned int u = __float_as_uint(f);
    u += 0x7FFFu + ((u >> 16) & 1u);      // RNE
    return (ushort_t)(u >> 16);
}
__device__ __forceinline__ float bf2f(ushort_t h){ return __uint_as_float(((unsigned int)h) << 16); }
__device__ __forceinline__ float bflo(unsigned int u){ return __uint_as_float(u << 16); }
__device__ __forceinline__ float bfhi(unsigned int u){ return __uint_as_float(u & 0xFFFF0000u); }

// fp8 e4m3 (OCP) helpers via HW converters
__device__ __forceinline__ unsigned int f4_to_fp8(float a, float b, float c, float d){
    int v = __builtin_amdgcn_cvt_pk_fp8_f32(a, b, 0, false);
    v = __builtin_amdgcn_cvt_pk_fp8_f32(c, d, v, true);
    return (unsigned int)v;
}
__device__ __forceinline__ void fp8_to_f4(unsigned int u, float& a, float& b, float& c, float& d){
    f32x2 lo = __builtin_amdgcn_cvt_pk_f32_fp8(u, false);
    f32x2 hi = __builtin_amdgcn_cvt_pk_f32_fp8(u, true);
    a = lo.x; b = lo.y; c = hi.x; d = hi.y;
}

// ---------------------------------------------------------------------------
// Prep: cast nf->bf16 (xb) + fp8 (xb8), bf16 weight tables, concat biases.
// (edge pass split back out — see k_deg / k_fill)
// ---------------------------------------------------------------------------
__global__ void k_prep(const float* __restrict__ nf,
                       const float* __restrict__ rgcn_w, const float* __restrict__ root,
                       const float* __restrict__ wq, const float* __restrict__ wk,
                       const float* __restrict__ wv, const float* __restrict__ wsk,
                       const float* __restrict__ bq, const float* __restrict__ bk,
                       const float* __restrict__ bv, const float* __restrict__ bsk,
                       const float* __restrict__ wl, const float* __restrict__ wr,
                       ushort_t* __restrict__ xb, uchar_t* __restrict__ xb8,
                       ushort_t* __restrict__ Wcat,
                       ushort_t* __restrict__ Wt2, float* __restrict__ bcat,
                       ushort_t* __restrict__ Wsage){
    int i = blockIdx.x*256 + threadIdx.x;
    const int NXB = NN*16;
    if (i < NXB){
        float4 v = ((const float4*)nf)[i];
        ushort4 h;
        h.x = f2bf(v.x); h.y = f2bf(v.y); h.z = f2bf(v.z); h.w = f2bf(v.w);
        ((ushort4*)xb)[i] = h;
        ((unsigned int*)xb8)[i] = f4_to_fp8(v.x, v.y, v.z, v.w);
        return;
    }
    int j = i - NXB;
    if (j < 64*576){
        int h = j / 576, k = j - h*576;
        float v = (k < 512) ? rgcn_w[(size_t)k*64 + h] : root[(size_t)(k-512)*64 + h];
        Wcat[j] = f2bf(v);
    } else if (j < 64*576 + 512*64){
        int jj = j - 64*576;
        int c = jj >> 6, k = jj & 63;
        int mt = c >> 7, cc = c & 127;
        const float* W = (mt==0)?wq:(mt==1)?wk:(mt==2)?wv:wsk;
        Wt2[jj] = f2bf(W[(size_t)k*128 + cc]);
    } else if (j < 64*576 + 512*64 + 512){
        int c = j - (64*576 + 512*64);
        int mt = c >> 7, cc = c & 127;
        const float* B = (mt==0)?bq:(mt==1)?bk:(mt==2)?bv:bsk;
        bcat[c] = B[cc];
    } else if (j < 64*576 + 512*64 + 512 + 32*256){
        int jj = j - (64*576 + 512*64 + 512);
        int c = jj >> 8, k = jj & 255;
        float v = (k < 128) ? wr[(size_t)k*32 + c] : wl[(size_t)(k-128)*32 + c];
        Wsage[jj] = f2bf(v);
    }
}

// fire-and-forget degree count (no return value -> wave never waits)
__global__ void k_deg(const int* __restrict__ ei, const int* __restrict__ et,
                      int* __restrict__ deg){
    int e = blockIdx.x*256 + threadIdx.x;
    if (e < NE)
        atomicAdd(&deg[ei[NE + e]*8 + et[e]], 1);
}

__global__ void k_scan1(const int* __restrict__ deg, int* __restrict__ tmp, int* __restrict__ bsum){
    __shared__ int s[SCAN_BS];
    int t = threadIdx.x;
    int i = blockIdx.x*SCAN_BS + t;
    s[t] = (i < NR) ? deg[i] : 0;
    __syncthreads();
    for (int off = 1; off < SCAN_BS; off <<= 1){
        int add = (t >= off) ? s[t-off] : 0;
        __syncthreads();
        s[t] += add;
        __syncthreads();
    }
    if (i < NR) tmp[i] = s[t];
    if (t == SCAN_BS-1) bsum[blockIdx.x] = s[t];
}

// parallel Hillis-Steele over 1024 slots (NB2=782 live)
__global__ void k_scan2(int* __restrict__ bsum){
    __shared__ int s[1024];
    int t = threadIdx.x;
    s[t] = (t < NB2) ? bsum[t] : 0;
    __syncthreads();
    for (int off = 1; off < 1024; off <<= 1){
        int v = (t >= off) ? s[t-off] : 0;
        __syncthreads();
        s[t] += v;
        __syncthreads();
    }
    if (t < NB2) bsum[t] = s[t];
}

__global__ void k_scan3(const int* __restrict__ tmp, const int* __restrict__ bsum,
                        int* __restrict__ rs, int* __restrict__ rs_cur){
    int i = blockIdx.x*256 + threadIdx.x;
    if (i < NR){
        int b = i >> 9;
        int off = (b > 0) ? bsum[b-1] : 0;
        int v = tmp[i] + off;
        rs[i+1] = v;
        rs_cur[i+1] = v;
        if (i == 0){ rs[0] = 0; rs_cur[0] = 0; }
    }
}

// slot via cursor atomic (rs_cur starts as a copy of rs); csr gets src id.
// within-segment order nondeterministic (was already, via old rank capture).
__global__ void k_fill(const int* __restrict__ ei, const int* __restrict__ et,
                       int* __restrict__ rs_cur, int* __restrict__ csr){
    int e = blockIdx.x*256 + threadIdx.x;
    if (e < NE){
        int seg = ei[NE + e]*8 + et[e];
        int pos = atomicAdd(&rs_cur[seg], 1);
        csr[pos] = ei[e];
    }
}

// ---------------------------------------------------------------------------
// FUSED RGCN. Phase 1: quad owns relations {quad,quad+4}; gather loop
// unrolled i+=4. Phase 2: 16x64 MFMA, K=576. Epilogue: h1pre write + bn1
// column stats into HIERARCHICAL partials (32 groups -> ~98 serial
// atomics/address, below the proven-safe 256 level).
// ---------------------------------------------------------------------------
__global__ __launch_bounds__(256) void rgcn_fused(const ushort_t* __restrict__ xb,
                                                  const uchar_t* __restrict__ xb8,
                                                  const int* __restrict__ rs,
                                                  const int* __restrict__ csr,
                                                  const ushort_t* __restrict__ Wcat,
                                                  const float* __restrict__ bias,
                                                  float* __restrict__ h1pre,
                                                  float* __restrict__ part1){
    __shared__ ushort_t Ml[16*520];
    int w = threadIdx.x >> 6, lane = threadIdx.x & 63;
    int quad = lane >> 4, l4 = lane & 15;
    int row0 = blockIdx.x * 16;                 // 3125*16 == 50000 exactly
    int n0 = row0 + w*4;
    int rsel = (lane < 9 ? lane : 8);
    int rb = rs[n0*8 + rsel];
    int eb0 = __shfl(rb, 0);
    int dg0 = __shfl(rb, 8) - eb0;
    int idx = (lane < dg0) ? csr[eb0 + lane] : 0;
    for (int j = 0; j < 4; ++j){
        int lrow = (w*4 + j)*520;
        int ebase = __shfl(rb, 0);
        int enext = __shfl(rb, 8);
        int rb_next = 0, idxn = 0;
        if (j < 3){
            rb_next = rs[(n0 + j + 1)*8 + rsel];
            idxn = csr[min(enext + lane, NE - 1)];   // addr independent of rb_next
        }
        int e0a = __shfl(rb, quad),     e1a = __shfl(rb, quad + 1);
        int e0b = __shfl(rb, quad + 4), e1b = __shfl(rb, quad + 5);
        int oa = e0a - ebase, la = e1a - e0a;
        int ob = e0b - ebase, lb = e1b - e0b;
        int laf = min(la, max(64 - oa, 0));
        int lbf = min(lb, max(64 - ob, 0));
        int ml = max(laf, lbf);
        ml = max(ml, __shfl_xor(ml, 16));
        ml = max(ml, __shfl_xor(ml, 32));
        f32x2 aA0 = {0.f,0.f}, aA1 = {0.f,0.f};
        f32x2 aB0 = {0.f,0.f}, aB1 = {0.f,0.f};
        for (int i = 0; i < ml; i += 4){
            unsigned int uA[4], uB[4];
#pragma unroll
            for (int u = 0; u < 4; ++u){
                int jA = oa + i + u, jB = ob + i + u;
                int tA = __shfl(idx, jA & 63);
                int tB = __shfl(idx, jB & 63);
                tA = ((i + u) < laf) ? tA : 0;       // row 0: L1-hot dummy
                tB = ((i + u) < lbf) ? tB : 0;
                uA[u] = *(const unsigned int*)(xb8 + (size_t)tA*64 + l4*4);
                uB[u] = *(const unsigned int*)(xb8 + (size_t)tB*64 + l4*4);
            }
#pragma unroll
            for (int u = 0; u < 4; ++u){
                unsigned int a = ((i + u) < laf) ? uA[u] : 0u;   // fp8 0x00 == 0.0f
                unsigned int b = ((i + u) < lbf) ? uB[u] : 0u;
                aA0 += __builtin_amdgcn_cvt_pk_f32_fp8(a, false);
                aA1 += __builtin_amdgcn_cvt_pk_f32_fp8(a, true);
                aB0 += __builtin_amdgcn_cvt_pk_f32_fp8(b, false);
                aB1 += __builtin_amdgcn_cvt_pk_f32_fp8(b, true);
            }
        }
        // rare tail: slots past the 64-entry idx window (node deg > 64)
        for (int i = laf; i < la; ++i){
            int t = csr[e0a + i];
            unsigned int a = *(const unsigned int*)(xb8 + (size_t)t*64 + l4*4);
            aA0 += __builtin_amdgcn_cvt_pk_f32_fp8(a, false);
            aA1 += __builtin_amdgcn_cvt_pk_f32_fp8(a, true);
        }
        for (int i = lbf; i < lb; ++i){
            int t = csr[e0b + i];
            unsigned int b = *(const unsigned int*)(xb8 + (size_t)t*64 + l4*4);
            aB0 += __builtin_amdgcn_cvt_pk_f32_fp8(b, false);
            aB1 += __builtin_amdgcn_cvt_pk_f32_fp8(b, true);
        }
        float inva = 1.f / fmaxf((float)la, 1.f);
        float invb = 1.f / fmaxf((float)lb, 1.f);
        ushort4 oA, oB;
        oA.x = f2bf(aA0.x*inva); oA.y = f2bf(aA0.y*inva); oA.z = f2bf(aA1.x*inva); oA.w = f2bf(aA1.y*inva);
        oB.x = f2bf(aB0.x*invb); oB.y = f2bf(aB0.y*invb); oB.z = f2bf(aB1.x*invb); oB.w = f2bf(aB1.y*invb);
        *(ushort4*)&Ml[lrow + quad*64 + l4*4] = oA;
        *(ushort4*)&Ml[lrow + (quad + 4)*64 + l4*4] = oB;
        if (j < 3){
            rb = rb_next;
            int ebn = __shfl(rb, 0);
            int dgn = __shfl(rb, 8) - ebn;
            idx = (lane < dgn) ? idxn : 0;
        }
    }
    __syncthreads();
    int m = l4;
    f32x4 acc = {};
#pragma unroll
    for (int kt = 0; kt < 18; ++kt){
        int kk = kt*32 + quad*8;
        bf16x8 a;
        if (kt < 16) a = *(const bf16x8*)&Ml[m*520 + kk];
        else         a = *(const bf16x8*)(xb + (size_t)(row0 + m)*64 + (kk - 512));
        bf16x8 b = *(const bf16x8*)(Wcat + (size_t)(w*16 + m)*576 + kk);
        acc = __builtin_amdgcn_mfma_f32_16x16x32_bf16(a, b, acc, 0, 0, 0);
    }
    int col = w*16 + m;
    float bz = bias[col];
    float s = 0.f, q = 0.f;
#pragma unroll
    for (int i = 0; i < 4; ++i){
        int rr = row0 + quad*4 + i;
        float y = acc[i] + bz;
        h1pre[(size_t)rr*64 + col] = y;
        s += y; q += y*y;
    }
    s += __shfl_xor(s, 16); q += __shfl_xor(q, 16);
    s += __shfl_xor(s, 32); q += __shfl_xor(q, 32);
    if (quad == 0){
        float* pg = part1 + (blockIdx.x & 31)*128;
        atomicAdd(&pg[col], s);
        atomicAdd(&pg[64 + col], q);
    }
}

// ---------------------------------------------------------------------------
// MFMA GEMM 2 (both col-groups in ONE kernel): Wt2 tile staged per cg with
// barriers; bn1 partials reduced block-cooperatively into LDS (L2-hot);
// h1pre/nf read once. k AND v stored as fp8.
// ---------------------------------------------------------------------------
#define QS 132   // pl row stride (ushorts)
#define BS 68    // Bs row stride (ushorts): 2-way bank alias (free, m136)
__global__ __launch_bounds__(256) void gemm_qkvs(const float* __restrict__ h1pre,
                                                 const float* __restrict__ nf,
                                                 const float* __restrict__ part1,
                                                 const float* __restrict__ g1, const float* __restrict__ b1,
                                                 const ushort_t* __restrict__ Wt2,
                                                 const float* __restrict__ bcat,
                                                 ushort_t* __restrict__ qb,
                                                 uchar_t* __restrict__ kb8,
                                                 uchar_t* __restrict__ vb8,
                                                 ushort_t* __restrict__ sb){
    __shared__ ushort_t Bs[256*BS];
    __shared__ ushort_t pl[4][16*QS];
    __shared__ float sred[128];
    int w = threadIdx.x >> 6, lane = threadIdx.x & 63;
    int m = lane & 15, quad = lane >> 4;
    int r0 = blockIdx.x*64 + w*16;
    int row = r0 + m;
    // ---- reduce bn1 partials (32 groups x 128, L2-hot) ----
    {
        int t = threadIdx.x;
        if (t < 128){
            float acc = 0.f;
#pragma unroll
            for (int g = 0; g < 32; ++g) acc += part1[g*128 + t];
            sred[t] = acc;
        }
    }
    __syncthreads();
    // ---- prologue (once): x1 fragments = bf16(leaky(bn1(h)) + nf) ----
    bf16x8 afrag[2];
#pragma unroll
    for (int kt = 0; kt < 2; ++kt){
        int db = kt*32 + quad*8;
        bf16x8 f = (bf16x8){0,0,0,0,0,0,0,0};
        if (row < NN){
            float4 h0 = *(const float4*)(h1pre + (size_t)row*64 + db);
            float4 h1 = *(const float4*)(h1pre + (size_t)row*64 + db + 4);
            float4 n0 = *(const float4*)(nf + (size_t)row*64 + db);
            float4 n1 = *(const float4*)(nf + (size_t)row*64 + db + 4);
            float4 ga = *(const float4*)(g1 + db);
            float4 gb_ = *(const float4*)(g1 + db + 4);
            float4 ba = *(const float4*)(b1 + db);
            float4 bb_ = *(const float4*)(b1 + db + 4);
            float hh[8] = {h0.x,h0.y,h0.z,h0.w,h1.x,h1.y,h1.z,h1.w};
            float nn[8] = {n0.x,n0.y,n0.z,n0.w,n1.x,n1.y,n1.z,n1.w};
            float GG[8] = {ga.x,ga.y,ga.z,ga.w,gb_.x,gb_.y,gb_.z,gb_.w};
            float BB[8] = {ba.x,ba.y,ba.z,ba.w,bb_.x,bb_.y,bb_.z,bb_.w};
#pragma unroll
            for (int e = 0; e < 8; ++e){
                float mm = sred[db + e] * INV_N;
                float vv = sred[64 + db + e] * INV_N - mm*mm;
                float A = rsqrtf(fmaxf(vv, 0.f) + BN_EPS) * GG[e];
                float C = BB[e] - mm * A;
                float y = fmaf(hh[e], A, C);
                y = (y >= 0.f) ? y : 0.01f*y;
                f[e] = (short)f2bf(y + nn[e]);
            }
        }
        afrag[kt] = f;
    }
    for (int cg = 0; cg < 2; ++cg){
        __syncthreads();     // prior cg's Bs reads (and sred reads) complete
        // ---- stage Wt2 col-group tile: 256 rows x 64 ush = 2048 uint4 ----
        {
            int t = threadIdx.x;
            const ushort_t* wsrc = Wt2 + (size_t)cg*256*64;
#pragma unroll
            for (int u0 = 0; u0 < 8; ++u0){
                int u = u0*256 + t;
                int r = u >> 3, c8 = (u & 7)*8;
                *(uint4*)&Bs[r*BS + c8] = *(const uint4*)(wsrc + u*8);
            }
        }
        __syncthreads();
        f32x4 acc[16] = {};
#pragma unroll
        for (int kt = 0; kt < 2; ++kt){
            int kk = kt*32 + quad*8;
#pragma unroll
            for (int ct = 0; ct < 16; ++ct){
                bf16x8 b = *(const bf16x8*)&Bs[(size_t)(ct*16 + m)*BS + kk];
                acc[ct] = __builtin_amdgcn_mfma_f32_16x16x32_bf16(afrag[kt], b, acc[ct], 0, 0, 0);
            }
        }
        // ---- half 0 (ct 0..7): cg0 -> q (bf16), cg1 -> v (fp8) ----
#pragma unroll
        for (int ct = 0; ct < 8; ++ct){
            int g = cg*256 + ct*16 + m;
            float bz = bcat[g];
            int cc = g & 127;
#pragma unroll
            for (int i = 0; i < 4; ++i)
                pl[w][(quad*4 + i)*QS + cc] = f2bf(acc[ct][i] + bz);
        }
        if (cg == 0){
#pragma unroll
            for (int t = 0; t < 4; ++t){
                int u = t*64 + lane;
                int r = u >> 4, c = (u & 15)*8;
                int gr = r0 + r;
                if (gr < NN) *(uint4*)(qb + (size_t)gr*128 + c) = *(const uint4*)&pl[w][r*QS + c];
            }
        } else {
#pragma unroll
            for (int t = 0; t < 4; ++t){
                int u = t*64 + lane;
                int r = u >> 4, c = (u & 15)*8;
                int gr = r0 + r;
                if (gr < NN){
                    uint4 vv4 = *(const uint4*)&pl[w][r*QS + c];
                    uint2 o;
                    o.x = f4_to_fp8(bflo(vv4.x), bfhi(vv4.x), bflo(vv4.y), bfhi(vv4.y));
                    o.y = f4_to_fp8(bflo(vv4.z), bfhi(vv4.z), bflo(vv4.w), bfhi(vv4.w));
                    *(uint2*)(vb8 + (size_t)gr*128 + c) = o;
                }
            }
        }
        // ---- half 1 (ct 8..15): cg0 -> k (fp8), cg1 -> skip ----
#pragma unroll
        for (int ct = 8; ct < 16; ++ct){
            int g = cg*256 + ct*16 + m;
            float bz = bcat[g];
            int cc = g & 127;
#pragma unroll
            for (int i = 0; i < 4; ++i)
                pl[w][(quad*4 + i)*QS + cc] = f2bf(acc[ct][i] + bz);
        }
        if (cg == 0){
#pragma unroll
            for (int t = 0; t < 4; ++t){
                int u = t*64 + lane;
                int r = u >> 4, c = (u & 15)*8;
                int gr = r0 + r;
                if (gr < NN){
                    uint4 kk4 = *(const uint4*)&pl[w][r*QS + c];
                    uint2 o;
                    o.x = f4_to_fp8(bflo(kk4.x), bfhi(kk4.x), bflo(kk4.y), bfhi(kk4.y));
                    o.y = f4_to_fp8(bflo(kk4.z), bfhi(kk4.z), bflo(kk4.w), bfhi(kk4.w));
                    *(uint2*)(kb8 + (size_t)gr*128 + c) = o;
                }
            }
        } else {
#pragma unroll
            for (int t = 0; t < 4; ++t){
                int u = t*64 + lane;
                int r = u >> 4, c = (u & 15)*8;
                int gr = r0 + r;
                if (gr < NN) *(uint4*)(sb + (size_t)gr*128 + c) = *(const uint4*)&pl[w][r*QS + c];
            }
        }
    }
}

// reduce bn1 partials (32x128) -> bns[0..127]; bn2 partials (64x256) -> bns[128..383]
__global__ void k_red2(const float* __restrict__ part1, const float* __restrict__ part2,
                       float* __restrict__ bns){
    int t = threadIdx.x;   // 256
    float acc = 0.f;
    for (int g = 0; g < 64; ++g) acc += part2[g*256 + t];
    bns[128 + t] = acc;
    if (t < 128){
        float a1 = 0.f;
        for (int g = 0; g < 32; ++g) a1 += part1[g*128 + t];
        bns[t] = a1;
    }
}

// ---------------------------------------------------------------------------
// MFMA GEMM 3: h3 = [x2b | nmeanb](50000x256) @ Wsage^T + bl  (32 cols)
// + bn3 stats into hierarchical partials (4 groups -> ~196/address).
// ---------------------------------------------------------------------------
__global__ __launch_bounds__(256) void sage_gemm(const ushort_t* __restrict__ x2b,
                                                 const ushort_t* __restrict__ nmeanb,
                                                 const ushort_t* __restrict__ Wsage,
                                                 const float* __restrict__ bl,
                                                 float* __restrict__ h3,
                                                 float* __restrict__ part3){
    int wv = threadIdx.x >> 6, lane = threadIdx.x & 63;
    int r0 = blockIdx.x*64 + wv*16;
    int m = lane & 15, quad = lane >> 4;
    int row = r0 + m;
    f32x4 acc[2] = {};
#pragma unroll
    for (int kt = 0; kt < 8; ++kt){
        int kk = kt*32 + quad*8;
        bf16x8 a;
        if (row < NN){
            const ushort_t* ap = (kt < 4) ? (x2b + (size_t)row*128 + kk)
                                          : (nmeanb + (size_t)row*128 + (kk - 128));
            a = *(const bf16x8*)ap;
        } else {
            a = (bf16x8){0,0,0,0,0,0,0,0};
        }
#pragma unroll
        for (int ct = 0; ct < 2; ++ct){
            bf16x8 b = *(const bf16x8*)(Wsage + (size_t)(ct*16 + m)*256 + kk);
            acc[ct] = __builtin_amdgcn_mfma_f32_16x16x32_bf16(a, b, acc[ct], 0, 0, 0);
        }
    }
    float s[2] = {0.f, 0.f}, q[2] = {0.f, 0.f};
#pragma unroll
    for (int ct = 0; ct < 2; ++ct){
        int col = ct*16 + m;
        float bz = bl[col];
#pragma unroll
        for (int i = 0; i < 4; ++i){
            int rr = r0 + quad*4 + i;
            if (rr < NN){
                float y = acc[ct][i] + bz;
                h3[(size_t)rr*32 + col] = y;
                s[ct] += y; q[ct] += y*y;
            }
        }
    }
#pragma unroll
    for (int ct = 0; ct < 2; ++ct){
        s[ct] += __shfl_xor(s[ct], 16); q[ct] += __shfl_xor(q[ct], 16);
        s[ct] += __shfl_xor(s[ct], 32); q[ct] += __shfl_xor(q[ct], 32);
    }
    if (quad == 0){
        float* pg = part3 + (blockIdx.x & 3)*64;
#pragma unroll
        for (int ct = 0; ct < 2; ++ct){
            int col = ct*16 + m;
            atomicAdd(&pg[col], s[ct]);
            atomicAdd(&pg[32 + col], q[ct]);
        }
    }
}

__device__ __forceinline__ float bn_leaky(float z, float m, float rsv, float g, float b){
    float y = (z - m) * rsv * g + b;
    return y >= 0.f ? y : 0.01f * y;
}

// x2 = leaky(bn2(h2)) + (c<64 ? x1 : 0); -> bf16 x2b, fp8 x28, cols<32 fp32 x2r
__global__ void bn_apply2(const float* __restrict__ h2, const float* __restrict__ h1pre,
                          const float* __restrict__ nf,
                          const float* __restrict__ g1, const float* __restrict__ b1,
                          const float* __restrict__ s1, const float* __restrict__ q1,
                          const float* __restrict__ g2, const float* __restrict__ b2,
                          const float* __restrict__ s2, const float* __restrict__ q2,
                          float* __restrict__ x2r, ushort_t* __restrict__ x2b,
                          uchar_t* __restrict__ x28){
    int i = blockIdx.x*256 + threadIdx.x;
    if (i >= NN*128) return;
    int n = i >> 7, c = i & 127;
    float m2 = s2[c] * INV_N;
    float v2 = q2[c] * INV_N - m2*m2;
    float rsv2 = rsqrtf(fmaxf(v2, 0.f) + BN_EPS);
    float val = bn_leaky(h2[i], m2, rsv2, g2[c], b2[c]);
    if (c < 64){
        float m1 = s1[c] * INV_N;
        float v1 = q1[c] * INV_N - m1*m1;
        float rsv1 = rsqrtf(fmaxf(v1, 0.f) + BN_EPS);
        val += bn_leaky(h1pre[(size_t)n*64 + c], m1, rsv1, g1[c], b1[c]) + nf[(size_t)n*64 + c];
    }
    if (c < 32) x2r[(size_t)n*32 + c] = val;
    x2b[i] = f2bf(val);
    int p = __builtin_amdgcn_cvt_pk_fp8_f32(val, val, 0, false);
    x28[i] = (uchar_t)(p & 0xFF);
}

// bn3 finals reduced inline from 4 hot-L2 partial groups
__global__ void bn_apply3(const float* __restrict__ h3, const float* __restrict__ x2r,
                          const float* __restrict__ g, const float* __restrict__ b,
                          const float* __restrict__ part3,
                          float* __restrict__ out){
    int i = blockIdx.x*256 + threadIdx.x;
    if (i >= NN*32) return;
    int c = i & 31;
    float s = 0.f, q = 0.f;
#pragma unroll
    for (int gg = 0; gg < 4; ++gg){
        s += part3[gg*64 + c];
        q += part3[gg*64 + 32 + c];
    }
    float m = s * INV_N;
    float v = q * INV_N - m*m;
    float rsv = rsqrtf(fmaxf(v, 0.f) + BN_EPS);
    out[i] = bn_leaky(h3[i], m, rsv, g[c], b[c]) + x2r[i];
}

// ---------------------------------------------------------------------------
// Attention: wave per dst node, CSR prefetch, 4 edges per half-wave in
// flight. k AND v gathered as fp8 (4 B/lane each) — 256 B/edge.
// Writes h2 = sb (skip) + attention output + bn2 stats into hierarchical
// partials (64 groups -> ~195 serial atomics/address).
// ---------------------------------------------------------------------------
__global__ __launch_bounds__(256) void attn_kernel(const ushort_t* __restrict__ qb,
                                                   const uchar_t* __restrict__ kb8,
                                                   const uchar_t* __restrict__ vb8,
                                                   const ushort_t* __restrict__ sb,
                                                   const int* __restrict__ rs,
                                                   const int* __restrict__ csr,
                                                   float* __restrict__ h2,
                                                   float* __restrict__ part2){
    __shared__ float sm[2][4][128];
    int w = threadIdx.x >> 6, lane = threadIdx.x & 63;
    int n = blockIdx.x*4 + w;                    // grid 12500*4 == 50000 exactly
    int half = lane >> 5, l5 = lane & 31;
    int e0 = rs[n*8], e1 = rs[n*8 + 8];
    int deg = e1 - e0;
    uint2 qu = *(const uint2*)(qb + (size_t)n*128 + l5*4);
    uint2 sbv = *(const uint2*)(sb + (size_t)n*128 + l5*4);
    float q0 = bflo(qu.x), q1 = bfhi(qu.x), q2 = bflo(qu.y), q3 = bfhi(qu.y);
    const float scale = 0.17677669529663687f;   // 1/sqrt(32)
    int idx = 0;
    if (lane < deg) idx = csr[e0 + lane];
    int dcap = min(deg, 64);
    int nt = (dcap + 7) >> 3;
    float den = 0.f, a0 = 0.f, a1 = 0.f, a2 = 0.f, a3 = 0.f;
    for (int t = 0; t < nt; ++t){
        int i2 = t*8 + half*4;
        int j0 = i2, j1 = i2+1, j2 = i2+2, j3 = i2+3;
        bool v0 = j0 < dcap, v1 = j1 < dcap, v2 = j2 < dcap, v3 = j3 < dcap;
        int s0 = __shfl(idx, j0 & 63); s0 = v0 ? s0 : 0;
        int s1 = __shfl(idx, j1 & 63); s1 = v1 ? s1 : 0;
        int s2 = __shfl(idx, j2 & 63); s2 = v2 ? s2 : 0;
        int s3 = __shfl(idx, j3 & 63); s3 = v3 ? s3 : 0;
        unsigned int ku0 = *(const unsigned int*)(kb8 + (size_t)s0*128 + l5*4);
        unsigned int ku1 = *(const unsigned int*)(kb8 + (size_t)s1*128 + l5*4);
        unsigned int ku2 = *(const unsigned int*)(kb8 + (size_t)s2*128 + l5*4);
        unsigned int ku3 = *(const unsigned int*)(kb8 + (size_t)s3*128 + l5*4);
        unsigned int vu0 = *(const unsigned int*)(vb8 + (size_t)s0*128 + l5*4);
        unsigned int vu1 = *(const unsigned int*)(vb8 + (size_t)s1*128 + l5*4);
        unsigned int vu2 = *(const unsigned int*)(vb8 + (size_t)s2*128 + l5*4);
        unsigned int vu3 = *(const unsigned int*)(vb8 + (size_t)s3*128 + l5*4);
        float ka, kb_, kc, kd;
        fp8_to_f4(ku0, ka, kb_, kc, kd);
        float p0 = q0*ka + q1*kb_ + q2*kc + q3*kd;
        fp8_to_f4(ku1, ka, kb_, kc, kd);
        float p1 = q0*ka + q1*kb_ + q2*kc + q3*kd;
        fp8_to_f4(ku2, ka, kb_, kc, kd);
        float p2 = q0*ka + q1*kb_ + q2*kc + q3*kd;
        fp8_to_f4(ku3, ka, kb_, kc, kd);
        float p3 = q0*ka + q1*kb_ + q2*kc + q3*kd;
        p0 += __shfl_xor(p0, 1); p1 += __shfl_xor(p1, 1); p2 += __shfl_xor(p2, 1); p3 += __shfl_xor(p3, 1);
        p0 += __shfl_xor(p0, 2); p1 += __shfl_xor(p1, 2); p2 += __shfl_xor(p2, 2); p3 += __shfl_xor(p3, 2);
        p0 += __shfl_xor(p0, 4); p1 += __shfl_xor(p1, 4); p2 += __shfl_xor(p2, 4); p3 += __shfl_xor(p3, 4);
        float w0 = v0 ? __expf(p0 * scale) : 0.f;
        float w1 = v1 ? __expf(p1 * scale) : 0.f;
        float w2 = v2 ? __expf(p2 * scale) : 0.f;
        float w3 = v3 ? __expf(p3 * scale) : 0.f;
        den += w0 + w1 + w2 + w3;
        float va, vb_, vc, vd;
        fp8_to_f4(vu0, va, vb_, vc, vd);
        a0 = fmaf(w0, va, a0); a1 = fmaf(w0, vb_, a1); a2 = fmaf(w0, vc, a2); a3 = fmaf(w0, vd, a3);
        fp8_to_f4(vu1, va, vb_, vc, vd);
        a0 = fmaf(w1, va, a0); a1 = fmaf(w1, vb_, a1); a2 = fmaf(w1, vc, a2); a3 = fmaf(w1, vd, a3);
        fp8_to_f4(vu2, va, vb_, vc, vd);
        a0 = fmaf(w2, va, a0); a1 = fmaf(w2, vb_, a1); a2 = fmaf(w2, vc, a2); a3 = fmaf(w2, vd, a3);
        fp8_to_f4(vu3, va, vb_, vc, vd);
        a0 = fmaf(w3, va, a0); a1 = fmaf(w3, vb_, a1); a2 = fmaf(w3, vc, a2); a3 = fmaf(w3, vd, a3);
    }
    // tail: deg > 64 (rare). Half-uniform trip counts; shuffles stay in-half.
    for (int e = 64 + half; e < deg; e += 2){
        int s = csr[e0 + e];
        unsigned int ku = *(const unsigned int*)(kb8 + (size_t)s*128 + l5*4);
        unsigned int vu = *(const unsigned int*)(vb8 + (size_t)s*128 + l5*4);
        float ka, kb_, kc, kd;
        fp8_to_f4(ku, ka, kb_, kc, kd);
        float p = q0*ka + q1*kb_ + q2*kc + q3*kd;
        p += __shfl_xor(p, 1);
        p += __shfl_xor(p, 2);
        p += __shfl_xor(p, 4);
        float wg = __expf(p * scale);
        den += wg;
        float va, vb_, vc, vd;
        fp8_to_f4(vu, va, vb_, vc, vd);
        a0 = fmaf(wg, va, a0); a1 = fmaf(wg, vb_, a1); a2 = fmaf(wg, vc, a2); a3 = fmaf(wg, vd, a3);
    }
    den += __shfl_xor(den, 32);
    a0 += __shfl_xor(a0, 32); a1 += __shfl_xor(a1, 32);
    a2 += __shfl_xor(a2, 32); a3 += __shfl_xor(a3, 32);
    float inv = (den > 0.f) ? 1.f/den : 0.f;
    float o0 = bflo(sbv.x) + a0*inv;
    float o1 = bfhi(sbv.x) + a1*inv;
    float o2 = bflo(sbv.y) + a2*inv;
    float o3 = bfhi(sbv.y) + a3*inv;
    if (half == 0){
        float4 o; o.x = o0; o.y = o1; o.z = o2; o.w = o3;
        *(float4*)(h2 + (size_t)n*128 + l5*4) = o;
        float4 t; t.x = o0; t.y = o1; t.z = o2; t.w = o3;
        *(float4*)&sm[0][w][l5*4] = t;
    } else {
        float4 t; t.x = o0*o0; t.y = o1*o1; t.z = o2*o2; t.w = o3*o3;
        *(float4*)&sm[1][w][l5*4] = t;
    }
    __syncthreads();
    // fused bn2 stats -> hierarchical partial group (blockIdx & 63)
    {
        int t = threadIdx.x;
        int st = t >> 7, c = t & 127;
        float v = sm[st][0][c] + sm[st][1][c] + sm[st][2][c] + sm[st][3][c];
        atomicAdd(&part2[(blockIdx.x & 63)*256 + st*128 + c], v);
    }
}

// ---------------------------------------------------------------------------
// SAGE mean aggregation: CSR prefetch, 4 edges/half, fp8 gathers (4 B/lane)
// ---------------------------------------------------------------------------
__global__ __launch_bounds__(256) void sage_agg(const uchar_t* __restrict__ x28,
                                                const int* __restrict__ rs,
                                                const int* __restrict__ csr,
                                                ushort_t* __restrict__ nmeanb){
    int w = threadIdx.x >> 6, lane = threadIdx.x & 63;
    int n = blockIdx.x*4 + w;
    if (n >= NN) return;
    int half = lane >> 5, l5 = lane & 31;
    int e0 = rs[n*8], e1 = rs[n*8 + 8];
    int deg = e1 - e0;
    int idx = 0;
    if (lane < deg) idx = csr[e0 + lane];
    int dcap = min(deg, 64);
    int nt = (dcap + 7) >> 3;
    f32x2 A0 = {0.f,0.f}, A1 = {0.f,0.f};
    for (int t = 0; t < nt; ++t){
        int i2 = t*8 + half*4;
        int j0 = i2, j1 = i2+1, j2 = i2+2, j3 = i2+3;
        bool v0 = j0 < dcap, v1 = j1 < dcap, v2 = j2 < dcap, v3 = j3 < dcap;
        int s0 = __shfl(idx, j0 & 63); s0 = v0 ? s0 : 0;
        int s1 = __shfl(idx, j1 & 63); s1 = v1 ? s1 : 0;
        int s2 = __shfl(idx, j2 & 63); s2 = v2 ? s2 : 0;
        int s3 = __shfl(idx, j3 & 63); s3 = v3 ? s3 : 0;
        unsigned int u0 = *(const unsigned int*)(x28 + (size_t)s0*128 + l5*4);
        unsigned int u1 = *(const unsigned int*)(x28 + (size_t)s1*128 + l5*4);
        unsigned int u2 = *(const unsigned int*)(x28 + (size_t)s2*128 + l5*4);
        unsigned int u3 = *(const unsigned int*)(x28 + (size_t)s3*128 + l5*4);
        u0 = v0 ? u0 : 0u; u1 = v1 ? u1 : 0u;
        u2 = v2 ? u2 : 0u; u3 = v3 ? u3 : 0u;
        A0 += __builtin_amdgcn_cvt_pk_f32_fp8(u0, false);
        A1 += __builtin_amdgcn_cvt_pk_f32_fp8(u0, true);
        A0 += __builtin_amdgcn_cvt_pk_f32_fp8(u1, false);
        A1 += __builtin_amdgcn_cvt_pk_f32_fp8(u1, true);
        A0 += __builtin_amdgcn_cvt_pk_f32_fp8(u2, false);
        A1 += __builtin_amdgcn_cvt_pk_f32_fp8(u2, true);
        A0 += __builtin_amdgcn_cvt_pk_f32_fp8(u3, false);
        A1 += __builtin_amdgcn_cvt_pk_f32_fp8(u3, true);
    }
    for (int e = 64 + half; e < deg; e += 2){
        int s = csr[e0 + e];
        unsigned int u = *(const unsigned int*)(x28 + (size_t)s*128 + l5*4);
        A0 += __builtin_amdgcn_cvt_pk_f32_fp8(u, false);
        A1 += __builtin_amdgcn_cvt_pk_f32_fp8(u, true);
    }
    float a0 = A0.x, a1 = A0.y, a2 = A1.x, a3 = A1.y;
    a0 += __shfl_xor(a0, 32); a1 += __shfl_xor(a1, 32);
    a2 += __shfl_xor(a2, 32); a3 += __shfl_xor(a3, 32);
    if (half == 0){
        float inv = 1.f / fmaxf((float)deg, 1.f);
        ushort4 o;
        o.x = f2bf(a0*inv); o.y = f2bf(a1*inv); o.z = f2bf(a2*inv); o.w = f2bf(a3*inv);
        *(ushort4*)(nmeanb + (size_t)n*128 + l5*4) = o;
    }
}

// ---------------------------------------------------------------------------
extern "C" void kernel_launch(void* const* d_in, const int* in_sizes, int n_in,
                              void* d_out, int out_size, void* d_ws, size_t ws_size,
                              hipStream_t stream){
    const float* nf      = (const float*)d_in[0];
    const int*   ei      = (const int*)d_in[2];
    const int*   et      = (const int*)d_in[3];
    const float* rgcn_w  = (const float*)d_in[4];
    const float* root    = (const float*)d_in[5];
    const float* rbias   = (const float*)d_in[6];
    const float* bn1g    = (const float*)d_in[7];
    const float* bn1b    = (const float*)d_in[8];
    const float* wq      = (const float*)d_in[9];
    const float* bq      = (const float*)d_in[10];
    const float* wk      = (const float*)d_in[11];
    const float* bk      = (const float*)d_in[12];
    const float* wv      = (const float*)d_in[13];
    const float* bv      = (const float*)d_in[14];
    const float* wsk     = (const float*)d_in[15];
    const float* bsk     = (const float*)d_in[16];
    const float* bn2g    = (const float*)d_in[17];
    const float* bn2b    = (const float*)d_in[18];
    const float* wl      = (const float*)d_in[19];
    const float* bl      = (const float*)d_in[20];
    const float* wr      = (const float*)d_in[21];
    const float* bn3g    = (const float*)d_in[22];
    const float* bn3b    = (const float*)d_in[23];
    float* out = (float*)d_out;

    // ---- workspace carve (256B aligned) ----
    char* base = (char*)d_ws;
    size_t off = 0;
    auto take = [&](size_t bytes) -> char* {
        char* p = base + off;
        off += (bytes + 255) & ~(size_t)255;
        return p;
    };
    int*      deg    = (int*)take((size_t)NR*4);
    float*    bns    = (float*)take(1024*4);
    float*    part1  = (float*)take(32*128*4);              // bn1 partials (16 KB)
    float*    part2  = (float*)take(64*256*4);              // bn2 partials (64 KB)
    float*    part3  = (float*)take(4*64*4);                // bn3 partials (1 KB)
    char*     zend   = base + off;                     // zero [deg, zend) in one memset
    int*      rs     = (int*)take((size_t)(NR+1)*4);
    int*      rs_cur = (int*)take((size_t)(NR+1)*4);        // cursor copy for k_fill
    int*      tmp    = (int*)take((size_t)NR*4);
    int*      bsum   = (int*)take(1024*4);
    int*      csr    = (int*)take((size_t)NE*4);
    ushort_t* Wcat   = (ushort_t*)take(64*576*2);
    ushort_t* Wt2    = (ushort_t*)take(512*64*2);
    float*    bcat   = (float*)take(512*4);
    ushort_t* Wsage  = (ushort_t*)take(32*256*2);
    ushort_t* xb     = (ushort_t*)take((size_t)NN*64*2);
    uchar_t*  xb8    = (uchar_t*)take((size_t)NN*64);       // fp8 gather copy (3.2 MB)
    float*    h1pre  = (float*)take((size_t)NN*64*4);
    float*    h2     = (float*)take((size_t)NN*128*4);
    float*    x2r    = (float*)take((size_t)NN*32*4);
    ushort_t* sb     = (ushort_t*)take((size_t)NN*128*2);   // bf16 skip (12.8 MB)
    char*     bigA   = take((size_t)NN*512*2);              // 51.2 MB multi-use
    if (off > ws_size) return;

    // bigA aliases (byte offsets); lifetimes verified stage-by-stage:
    ushort_t* qb     = (ushort_t*)(bigA + (size_t)NN*128);       // gemm_qkvs -> attn (12.8 MB)
    uchar_t*  vb8    = (uchar_t*)(bigA + (size_t)NN*384);        // gemm_qkvs -> attn (6.4 MB)
    uchar_t*  kb8    = (uchar_t*)(bigA + (size_t)NN*640);        // gemm_qkvs -> attn (6.4 MB)
    ushort_t* x2b    = (ushort_t*)bigA;                          // bn_apply2 -> sage_gemm (12.8 MB)
    uchar_t*  x28    = (uchar_t*)(bigA + (size_t)NN*256);        // bn_apply2 -> sage_agg (6.4 MB)
    ushort_t* nmeanb = (ushort_t*)(bigA + (size_t)NN*512);       // sage_agg -> sage_gemm (12.8 MB)
    float*    h3     = (float*)(bigA + (size_t)NN*768);          // sage_gemm -> bn3 (6.4 MB)

    hipMemsetAsync(deg, 0, (size_t)(zend - (char*)deg), stream); // deg + bns + partials

    // ---- weight/node prep + CSR build (count -> scan -> cursor fill) ----
    const int PREP_N = NN*16 + 64*576 + 512*64 + 512 + 32*256;
    k_prep <<<(PREP_N+255)/256, 256, 0, stream>>>(nf, rgcn_w, root, wq, wk, wv, wsk,
                                                  bq, bk, bv, bsk, wl, wr,
                                                  xb, xb8, Wcat, Wt2, bcat, Wsage);
    k_deg  <<<(NE+255)/256, 256, 0, stream>>>(ei, et, deg);
    k_scan1<<<NB2, SCAN_BS, 0, stream>>>(deg, tmp, bsum);
    k_scan2<<<1, 1024, 0, stream>>>(bsum);
    k_scan3<<<(NR+255)/256, 256, 0, stream>>>(tmp, bsum, rs, rs_cur);
    k_fill <<<(NE+255)/256, 256, 0, stream>>>(ei, et, rs_cur, csr);

    const int NB4 = (NN + 3) / 4;
    const int NBG = (NN + 63) / 64;

    // ---- stage 1: RGCN (fused agg + MFMA + bn1 partial stats) ----
    rgcn_fused<<<NN/16, 256, 0, stream>>>(xb, xb8, rs, csr, Wcat, rbias, h1pre, part1);

    // ---- stage 2: TransformerConv ----
    gemm_qkvs<<<NBG, 256, 0, stream>>>(h1pre, nf, part1, bn1g, bn1b,
                                       Wt2, bcat, qb, kb8, vb8, sb);
    attn_kernel<<<NB4, 256, 0, stream>>>(qb, kb8, vb8, sb, rs, csr, h2, part2);
    k_red2<<<1, 256, 0, stream>>>(part1, part2, bns);
    bn_apply2<<<(NN*128+255)/256, 256, 0, stream>>>(h2, h1pre, nf,
                                                    bn1g, bn1b, bns + 0, bns + 64,
                                                    bn2g, bn2b, bns + 128, bns + 256,
                                                    x2r, x2b, x28);

    // ---- stage 3: SAGE ----
    sage_agg<<<NB4, 256, 0, stream>>>(x28, rs, csr, nmeanb);
    sage_gemm<<<NBG, 256, 0, stream>>>(x2b, nmeanb, Wsage, bl, h3, part3);
    bn_apply3<<<(NN*32+255)/256, 256, 0, stream>>>(h3, x2r, bn3g, bn3b, part3, out);
}

// Round 8
// 365.582 us; speedup vs baseline: 1.1142x; 1.1142x over previous
//
#include <hip/hip_runtime.h>
#include <stdint.h>

#define NN 50000
#define NE 800000
#define NR (NN*8)            // (node, relation) segments
#define SCAN_BS 512
#define NB2 782              // ceil(NR/512)
#define INV_N (1.0f/50000.0f)
#define BN_EPS 1e-5f

typedef unsigned short ushort_t;
typedef unsigned char uchar_t;
typedef short bf16x8 __attribute__((ext_vector_type(8)));   // 8 bf16 (4 VGPRs)
typedef float f32x4 __attribute__((ext_vector_type(4)));
typedef float f32x2 __attribute__((ext_vector_type(2)));

__device__ __forceinline__ ushort_t f2bf(float f){
    unsigned int u = __float_as_uint(f);
    u += 0x7FFFu + ((u >> 16) & 1u);      // RNE
    return (ushort_t)(u >> 16);
}
__device__ __forceinline__ float bf2f(ushort_t h){ return __uint_as_float(((unsigned int)h) << 16); }
__device__ __forceinline__ float bflo(unsigned int u){ return __uint_as_float(u << 16); }
__device__ __forceinline__ float bfhi(unsigned int u){ return __uint_as_float(u & 0xFFFF0000u); }

// fp8 e4m3 (OCP) helpers via HW converters
__device__ __forceinline__ unsigned int f4_to_fp8(float a, float b, float c, float d){
    int v = __builtin_amdgcn_cvt_pk_fp8_f32(a, b, 0, false);
    v = __builtin_amdgcn_cvt_pk_fp8_f32(c, d, v, true);
    return (unsigned int)v;
}
__device__ __forceinline__ void fp8_to_f4(unsigned int u, float& a, float& b, float& c, float& d){
    f32x2 lo = __builtin_amdgcn_cvt_pk_f32_fp8(u, false);
    f32x2 hi = __builtin_amdgcn_cvt_pk_f32_fp8(u, true);
    a = lo.x; b = lo.y; c = hi.x; d = hi.y;
}

// ---------------------------------------------------------------------------
// Prep (merged with k_deg): cast nf->bf16 (xb) + fp8 (xb8), bf16 weight
// tables, concat biases, AND per-(dst,rel) degree count + (seg,rank) capture.
// (R7's split CSR build regressed -30us: the edge atomic lost its BW overlap
// partner. Keep merged.)
// ---------------------------------------------------------------------------
__global__ void k_prep(const float* __restrict__ nf,
                       const float* __restrict__ rgcn_w, const float* __restrict__ root,
                       const float* __restrict__ wq, const float* __restrict__ wk,
                       const float* __restrict__ wv, const float* __restrict__ wsk,
                       const float* __restrict__ bq, const float* __restrict__ bk,
                       const float* __restrict__ bv, const float* __restrict__ bsk,
                       const float* __restrict__ wl, const float* __restrict__ wr,
                       const int* __restrict__ ei, const int* __restrict__ et,
                       int* __restrict__ deg, uint2* __restrict__ sr,
                       ushort_t* __restrict__ xb, uchar_t* __restrict__ xb8,
                       ushort_t* __restrict__ Wcat,
                       ushort_t* __restrict__ Wt2, float* __restrict__ bcat,
                       ushort_t* __restrict__ Wsage){
    int i = blockIdx.x*256 + threadIdx.x;
    const int NXB = NN*16;
    if (i < NXB){
        float4 v = ((const float4*)nf)[i];
        ushort4 h;
        h.x = f2bf(v.x); h.y = f2bf(v.y); h.z = f2bf(v.z); h.w = f2bf(v.w);
        ((ushort4*)xb)[i] = h;
        ((unsigned int*)xb8)[i] = f4_to_fp8(v.x, v.y, v.z, v.w);
        return;
    }
    int j = i - NXB;
    if (j < 64*576){
        int h = j / 576, k = j - h*576;
        float v = (k < 512) ? rgcn_w[(size_t)k*64 + h] : root[(size_t)(k-512)*64 + h];
        Wcat[j] = f2bf(v);
    } else if (j < 64*576 + 512*64){
        int jj = j - 64*576;
        int c = jj >> 6, k = jj & 63;
        int mt = c >> 7, cc = c & 127;
        const float* W = (mt==0)?wq:(mt==1)?wk:(mt==2)?wv:wsk;
        Wt2[jj] = f2bf(W[(size_t)k*128 + cc]);
    } else if (j < 64*576 + 512*64 + 512){
        int c = j - (64*576 + 512*64);
        int mt = c >> 7, cc = c & 127;
        const float* B = (mt==0)?bq:(mt==1)?bk:(mt==2)?bv:bsk;
        bcat[c] = B[cc];
    } else if (j < 64*576 + 512*64 + 512 + 32*256){
        int jj = j - (64*576 + 512*64 + 512);
        int c = jj >> 8, k = jj & 255;
        float v = (k < 128) ? wr[(size_t)k*32 + c] : wl[(size_t)(k-128)*32 + c];
        Wsage[jj] = f2bf(v);
    } else {
        int e = j - (64*576 + 512*64 + 512 + 32*256);
        if (e < NE){
            int seg = ei[NE + e]*8 + et[e];
            int rank = atomicAdd(&deg[seg], 1);
            uint2 o; o.x = (unsigned)seg; o.y = (unsigned)rank;
            sr[e] = o;
        }
    }
}

__global__ void k_scan1(const int* __restrict__ deg, int* __restrict__ tmp, int* __restrict__ bsum){
    __shared__ int s[SCAN_BS];
    int t = threadIdx.x;
    int i = blockIdx.x*SCAN_BS + t;
    s[t] = (i < NR) ? deg[i] : 0;
    __syncthreads();
    for (int off = 1; off < SCAN_BS; off <<= 1){
        int add = (t >= off) ? s[t-off] : 0;
        __syncthreads();
        s[t] += add;
        __syncthreads();
    }
    if (i < NR) tmp[i] = s[t];
    if (t == SCAN_BS-1) bsum[blockIdx.x] = s[t];
}

// parallel Hillis-Steele over 1024 slots (NB2=782 live)
__global__ void k_scan2(int* __restrict__ bsum){
    __shared__ int s[1024];
    int t = threadIdx.x;
    s[t] = (t < NB2) ? bsum[t] : 0;
    __syncthreads();
    for (int off = 1; off < 1024; off <<= 1){
        int v = (t >= off) ? s[t-off] : 0;
        __syncthreads();
        s[t] += v;
        __syncthreads();
    }
    if (t < NB2) bsum[t] = s[t];
}

__global__ void k_scan3(const int* __restrict__ tmp, const int* __restrict__ bsum, int* __restrict__ rs){
    int i = blockIdx.x*256 + threadIdx.x;
    if (i < NR){
        int b = i >> 9;
        int off = (b > 0) ? bsum[b-1] : 0;
        rs[i+1] = tmp[i] + off;
        if (i == 0) rs[0] = 0;
    }
}

// atomic-free: pos = rs[seg] + rank (deterministic, race-free)
__global__ void k_fill(const int* __restrict__ ei, const uint2* __restrict__ sr,
                       const int* __restrict__ rs, int* __restrict__ csr){
    int e = blockIdx.x*256 + threadIdx.x;
    if (e < NE){
        uint2 s = sr[e];
        csr[rs[s.x] + (int)s.y] = ei[e];
    }
}

// ---------------------------------------------------------------------------
// FUSED RGCN. Phase 1: quad owns ADJACENT relations {2q, 2q+1} and walks
// their CONCATENATED csr range (contiguous!) as one run of la+lb edges —
// halves gather-slot count vs lock-step max(la,lb) walk (4 loads/lane/trip
// instead of 8). A/B split via quad-uniform predicate j<la.
// Phase 2: 16x64 MFMA, K=576. Epilogue: h1pre + bn1 partial stats.
// ---------------------------------------------------------------------------
__global__ __launch_bounds__(256) void rgcn_fused(const ushort_t* __restrict__ xb,
                                                  const uchar_t* __restrict__ xb8,
                                                  const int* __restrict__ rs,
                                                  const int* __restrict__ csr,
                                                  const ushort_t* __restrict__ Wcat,
                                                  const float* __restrict__ bias,
                                                  float* __restrict__ h1pre,
                                                  float* __restrict__ part1){
    __shared__ ushort_t Ml[16*520];
    int w = threadIdx.x >> 6, lane = threadIdx.x & 63;
    int quad = lane >> 4, l4 = lane & 15;
    int row0 = blockIdx.x * 16;                 // 3125*16 == 50000 exactly
    int n0 = row0 + w*4;
    int rsel = (lane < 9 ? lane : 8);
    int rb = rs[n0*8 + rsel];
    int eb0 = __shfl(rb, 0);
    int dg0 = __shfl(rb, 8) - eb0;
    int idx = (lane < dg0) ? csr[eb0 + lane] : 0;
    for (int j = 0; j < 4; ++j){
        int lrow = (w*4 + j)*520;
        int ebase = __shfl(rb, 0);
        int enext = __shfl(rb, 8);
        int rb_next = 0, idxn = 0;
        if (j < 3){
            rb_next = rs[(n0 + j + 1)*8 + rsel];
            idxn = csr[min(enext + lane, NE - 1)];   // addr independent of rb_next
        }
        int e0a = __shfl(rb, 2*quad);
        int e1a = __shfl(rb, 2*quad + 1);
        int e2a = __shfl(rb, 2*quad + 2);
        int oa = e0a - ebase;                  // combined-range start offset
        int la = e1a - e0a, lb = e2a - e1a;
        int tot = la + lb;
        int fastN = min(tot, max(64 - oa, 0)); // slots resident in idx window
        int ml = fastN;
        ml = max(ml, __shfl_xor(ml, 16));
        ml = max(ml, __shfl_xor(ml, 32));
        f32x2 aA0 = {0.f,0.f}, aA1 = {0.f,0.f};
        f32x2 aB0 = {0.f,0.f}, aB1 = {0.f,0.f};
        for (int i = 0; i < ml; i += 4){
            unsigned int uX[4];
#pragma unroll
            for (int u = 0; u < 4; ++u){
                int jj = i + u;
                int t = __shfl(idx, (oa + jj) & 63);
                t = (jj < fastN) ? t : 0;            // row 0: L1-hot dummy
                uX[u] = *(const unsigned int*)(xb8 + (size_t)t*64 + l4*4);
            }
#pragma unroll
            for (int u = 0; u < 4; ++u){
                int jj = i + u;
                unsigned int a = (jj < fastN) ? uX[u] : 0u;   // fp8 0x00 == 0.0f
                f32x2 lo = __builtin_amdgcn_cvt_pk_f32_fp8(a, false);
                f32x2 hi = __builtin_amdgcn_cvt_pk_f32_fp8(a, true);
                if (jj < la){ aA0 += lo; aA1 += hi; }          // quad-uniform split
                else        { aB0 += lo; aB1 += hi; }
            }
        }
        // rare tails: combined slots past the 64-entry idx window
        for (int jj = min(la, fastN); jj < la; ++jj){
            int t = csr[e0a + jj];
            unsigned int a = *(const unsigned int*)(xb8 + (size_t)t*64 + l4*4);
            aA0 += __builtin_amdgcn_cvt_pk_f32_fp8(a, false);
            aA1 += __builtin_amdgcn_cvt_pk_f32_fp8(a, true);
        }
        for (int jj = max(la, fastN); jj < tot; ++jj){
            int t = csr[e0a + jj];
            unsigned int b = *(const unsigned int*)(xb8 + (size_t)t*64 + l4*4);
            aB0 += __builtin_amdgcn_cvt_pk_f32_fp8(b, false);
            aB1 += __builtin_amdgcn_cvt_pk_f32_fp8(b, true);
        }
        float inva = 1.f / fmaxf((float)la, 1.f);
        float invb = 1.f / fmaxf((float)lb, 1.f);
        ushort4 oA, oB;
        oA.x = f2bf(aA0.x*inva); oA.y = f2bf(aA0.y*inva); oA.z = f2bf(aA1.x*inva); oA.w = f2bf(aA1.y*inva);
        oB.x = f2bf(aB0.x*invb); oB.y = f2bf(aB0.y*invb); oB.z = f2bf(aB1.x*invb); oB.w = f2bf(aB1.y*invb);
        *(ushort4*)&Ml[lrow + (2*quad)*64 + l4*4] = oA;
        *(ushort4*)&Ml[lrow + (2*quad + 1)*64 + l4*4] = oB;
        if (j < 3){
            rb = rb_next;
            int ebn = __shfl(rb, 0);
            int dgn = __shfl(rb, 8) - ebn;
            idx = (lane < dgn) ? idxn : 0;
        }
    }
    __syncthreads();
    int m = l4;
    f32x4 acc = {};
#pragma unroll
    for (int kt = 0; kt < 18; ++kt){
        int kk = kt*32 + quad*8;
        bf16x8 a;
        if (kt < 16) a = *(const bf16x8*)&Ml[m*520 + kk];
        else         a = *(const bf16x8*)(xb + (size_t)(row0 + m)*64 + (kk - 512));
        bf16x8 b = *(const bf16x8*)(Wcat + (size_t)(w*16 + m)*576 + kk);
        acc = __builtin_amdgcn_mfma_f32_16x16x32_bf16(a, b, acc, 0, 0, 0);
    }
    int col = w*16 + m;
    float bz = bias[col];
    float s = 0.f, q = 0.f;
#pragma unroll
    for (int i = 0; i < 4; ++i){
        int rr = row0 + quad*4 + i;
        float y = acc[i] + bz;
        h1pre[(size_t)rr*64 + col] = y;
        s += y; q += y*y;
    }
    s += __shfl_xor(s, 16); q += __shfl_xor(q, 16);
    s += __shfl_xor(s, 32); q += __shfl_xor(q, 32);
    if (quad == 0){
        float* pg = part1 + (blockIdx.x & 31)*128;
        atomicAdd(&pg[col], s);
        atomicAdd(&pg[64 + col], q);
    }
}

// ---------------------------------------------------------------------------
// MFMA GEMM 2 (both col-groups in ONE kernel): Wt2 tile staged per cg with
// barriers; bn1 partials reduced block-cooperatively into LDS (L2-hot);
// h1pre/nf read once. k AND v stored as fp8.
// ---------------------------------------------------------------------------
#define QS 132   // pl row stride (ushorts)
#define BS 68    // Bs row stride (ushorts): 2-way bank alias (free, m136)
__global__ __launch_bounds__(256) void gemm_qkvs(const float* __restrict__ h1pre,
                                                 const float* __restrict__ nf,
                                                 const float* __restrict__ part1,
                                                 const float* __restrict__ g1, const float* __restrict__ b1,
                                                 const ushort_t* __restrict__ Wt2,
                                                 const float* __restrict__ bcat,
                                                 ushort_t* __restrict__ qb,
                                                 uchar_t* __restrict__ kb8,
                                                 uchar_t* __restrict__ vb8,
                                                 ushort_t* __restrict__ sb){
    __shared__ ushort_t Bs[256*BS];
    __shared__ ushort_t pl[4][16*QS];
    __shared__ float sred[128];
    int w = threadIdx.x >> 6, lane = threadIdx.x & 63;
    int m = lane & 15, quad = lane >> 4;
    int r0 = blockIdx.x*64 + w*16;
    int row = r0 + m;
    // ---- reduce bn1 partials (32 groups x 128, L2-hot) ----
    {
        int t = threadIdx.x;
        if (t < 128){
            float acc = 0.f;
#pragma unroll
            for (int g = 0; g < 32; ++g) acc += part1[g*128 + t];
            sred[t] = acc;
        }
    }
    __syncthreads();
    // ---- prologue (once): x1 fragments = bf16(leaky(bn1(h)) + nf) ----
    bf16x8 afrag[2];
#pragma unroll
    for (int kt = 0; kt < 2; ++kt){
        int db = kt*32 + quad*8;
        bf16x8 f = (bf16x8){0,0,0,0,0,0,0,0};
        if (row < NN){
            float4 h0 = *(const float4*)(h1pre + (size_t)row*64 + db);
            float4 h1 = *(const float4*)(h1pre + (size_t)row*64 + db + 4);
            float4 n0 = *(const float4*)(nf + (size_t)row*64 + db);
            float4 n1 = *(const float4*)(nf + (size_t)row*64 + db + 4);
            float4 ga = *(const float4*)(g1 + db);
            float4 gb_ = *(const float4*)(g1 + db + 4);
            float4 ba = *(const float4*)(b1 + db);
            float4 bb_ = *(const float4*)(b1 + db + 4);
            float hh[8] = {h0.x,h0.y,h0.z,h0.w,h1.x,h1.y,h1.z,h1.w};
            float nn[8] = {n0.x,n0.y,n0.z,n0.w,n1.x,n1.y,n1.z,n1.w};
            float GG[8] = {ga.x,ga.y,ga.z,ga.w,gb_.x,gb_.y,gb_.z,gb_.w};
            float BB[8] = {ba.x,ba.y,ba.z,ba.w,bb_.x,bb_.y,bb_.z,bb_.w};
#pragma unroll
            for (int e = 0; e < 8; ++e){
                float mm = sred[db + e] * INV_N;
                float vv = sred[64 + db + e] * INV_N - mm*mm;
                float A = rsqrtf(fmaxf(vv, 0.f) + BN_EPS) * GG[e];
                float C = BB[e] - mm * A;
                float y = fmaf(hh[e], A, C);
                y = (y >= 0.f) ? y : 0.01f*y;
                f[e] = (short)f2bf(y + nn[e]);
            }
        }
        afrag[kt] = f;
    }
    for (int cg = 0; cg < 2; ++cg){
        __syncthreads();     // prior cg's Bs reads (and sred reads) complete
        // ---- stage Wt2 col-group tile: 256 rows x 64 ush = 2048 uint4 ----
        {
            int t = threadIdx.x;
            const ushort_t* wsrc = Wt2 + (size_t)cg*256*64;
#pragma unroll
            for (int u0 = 0; u0 < 8; ++u0){
                int u = u0*256 + t;
                int r = u >> 3, c8 = (u & 7)*8;
                *(uint4*)&Bs[r*BS + c8] = *(const uint4*)(wsrc + u*8);
            }
        }
        __syncthreads();
        f32x4 acc[16] = {};
#pragma unroll
        for (int kt = 0; kt < 2; ++kt){
            int kk = kt*32 + quad*8;
#pragma unroll
            for (int ct = 0; ct < 16; ++ct){
                bf16x8 b = *(const bf16x8*)&Bs[(size_t)(ct*16 + m)*BS + kk];
                acc[ct] = __builtin_amdgcn_mfma_f32_16x16x32_bf16(afrag[kt], b, acc[ct], 0, 0, 0);
            }
        }
        // ---- half 0 (ct 0..7): cg0 -> q (bf16), cg1 -> v (fp8) ----
#pragma unroll
        for (int ct = 0; ct < 8; ++ct){
            int g = cg*256 + ct*16 + m;
            float bz = bcat[g];
            int cc = g & 127;
#pragma unroll
            for (int i = 0; i < 4; ++i)
                pl[w][(quad*4 + i)*QS + cc] = f2bf(acc[ct][i] + bz);
        }
        if (cg == 0){
#pragma unroll
            for (int t = 0; t < 4; ++t){
                int u = t*64 + lane;
                int r = u >> 4, c = (u & 15)*8;
                int gr = r0 + r;
                if (gr < NN) *(uint4*)(qb + (size_t)gr*128 + c) = *(const uint4*)&pl[w][r*QS + c];
            }
        } else {
#pragma unroll
            for (int t = 0; t < 4; ++t){
                int u = t*64 + lane;
                int r = u >> 4, c = (u & 15)*8;
                int gr = r0 + r;
                if (gr < NN){
                    uint4 vv4 = *(const uint4*)&pl[w][r*QS + c];
                    uint2 o;
                    o.x = f4_to_fp8(bflo(vv4.x), bfhi(vv4.x), bflo(vv4.y), bfhi(vv4.y));
                    o.y = f4_to_fp8(bflo(vv4.z), bfhi(vv4.z), bflo(vv4.w), bfhi(vv4.w));
                    *(uint2*)(vb8 + (size_t)gr*128 + c) = o;
                }
            }
        }
        // ---- half 1 (ct 8..15): cg0 -> k (fp8), cg1 -> skip ----
#pragma unroll
        for (int ct = 8; ct < 16; ++ct){
            int g = cg*256 + ct*16 + m;
            float bz = bcat[g];
            int cc = g & 127;
#pragma unroll
            for (int i = 0; i < 4; ++i)
                pl[w][(quad*4 + i)*QS + cc] = f2bf(acc[ct][i] + bz);
        }
        if (cg == 0){
#pragma unroll
            for (int t = 0; t < 4; ++t){
                int u = t*64 + lane;
                int r = u >> 4, c = (u & 15)*8;
                int gr = r0 + r;
                if (gr < NN){
                    uint4 kk4 = *(const uint4*)&pl[w][r*QS + c];
                    uint2 o;
                    o.x = f4_to_fp8(bflo(kk4.x), bfhi(kk4.x), bflo(kk4.y), bfhi(kk4.y));
                    o.y = f4_to_fp8(bflo(kk4.z), bfhi(kk4.z), bflo(kk4.w), bfhi(kk4.w));
                    *(uint2*)(kb8 + (size_t)gr*128 + c) = o;
                }
            }
        } else {
#pragma unroll
            for (int t = 0; t < 4; ++t){
                int u = t*64 + lane;
                int r = u >> 4, c = (u & 15)*8;
                int gr = r0 + r;
                if (gr < NN) *(uint4*)(sb + (size_t)gr*128 + c) = *(const uint4*)&pl[w][r*QS + c];
            }
        }
    }
}

// reduce bn1 partials (32x128) -> bns[0..127]; bn2 partials (64x256) -> bns[128..383]
__global__ void k_red2(const float* __restrict__ part1, const float* __restrict__ part2,
                       float* __restrict__ bns){
    int t = threadIdx.x;   // 256
    float acc = 0.f;
    for (int g = 0; g < 64; ++g) acc += part2[g*256 + t];
    bns[128 + t] = acc;
    if (t < 128){
        float a1 = 0.f;
        for (int g = 0; g < 32; ++g) a1 += part1[g*128 + t];
        bns[t] = a1;
    }
}

// ---------------------------------------------------------------------------
// MFMA GEMM 3: h3 = [x2b | nmeanb](50000x256) @ Wsage^T + bl  (32 cols)
// + bn3 stats into hierarchical partials (4 groups -> ~196/address).
// ---------------------------------------------------------------------------
__global__ __launch_bounds__(256) void sage_gemm(const ushort_t* __restrict__ x2b,
                                                 const ushort_t* __restrict__ nmeanb,
                                                 const ushort_t* __restrict__ Wsage,
                                                 const float* __restrict__ bl,
                                                 float* __restrict__ h3,
                                                 float* __restrict__ part3){
    int wv = threadIdx.x >> 6, lane = threadIdx.x & 63;
    int r0 = blockIdx.x*64 + wv*16;
    int m = lane & 15, quad = lane >> 4;
    int row = r0 + m;
    f32x4 acc[2] = {};
#pragma unroll
    for (int kt = 0; kt < 8; ++kt){
        int kk = kt*32 + quad*8;
        bf16x8 a;
        if (row < NN){
            const ushort_t* ap = (kt < 4) ? (x2b + (size_t)row*128 + kk)
                                          : (nmeanb + (size_t)row*128 + (kk - 128));
            a = *(const bf16x8*)ap;
        } else {
            a = (bf16x8){0,0,0,0,0,0,0,0};
        }
#pragma unroll
        for (int ct = 0; ct < 2; ++ct){
            bf16x8 b = *(const bf16x8*)(Wsage + (size_t)(ct*16 + m)*256 + kk);
            acc[ct] = __builtin_amdgcn_mfma_f32_16x16x32_bf16(a, b, acc[ct], 0, 0, 0);
        }
    }
    float s[2] = {0.f, 0.f}, q[2] = {0.f, 0.f};
#pragma unroll
    for (int ct = 0; ct < 2; ++ct){
        int col = ct*16 + m;
        float bz = bl[col];
#pragma unroll
        for (int i = 0; i < 4; ++i){
            int rr = r0 + quad*4 + i;
            if (rr < NN){
                float y = acc[ct][i] + bz;
                h3[(size_t)rr*32 + col] = y;
                s[ct] += y; q[ct] += y*y;
            }
        }
    }
#pragma unroll
    for (int ct = 0; ct < 2; ++ct){
        s[ct] += __shfl_xor(s[ct], 16); q[ct] += __shfl_xor(q[ct], 16);
        s[ct] += __shfl_xor(s[ct], 32); q[ct] += __shfl_xor(q[ct], 32);
    }
    if (quad == 0){
        float* pg = part3 + (blockIdx.x & 3)*64;
#pragma unroll
        for (int ct = 0; ct < 2; ++ct){
            int col = ct*16 + m;
            atomicAdd(&pg[col], s[ct]);
            atomicAdd(&pg[32 + col], q[ct]);
        }
    }
}

__device__ __forceinline__ float bn_leaky(float z, float m, float rsv, float g, float b){
    float y = (z - m) * rsv * g + b;
    return y >= 0.f ? y : 0.01f * y;
}

// x2 = leaky(bn2(h2)) + (c<64 ? x1 : 0); -> bf16 x2b, fp8 x28, cols<32 fp32 x2r
__global__ void bn_apply2(const float* __restrict__ h2, const float* __restrict__ h1pre,
                          const float* __restrict__ nf,
                          const float* __restrict__ g1, const float* __restrict__ b1,
                          const float* __restrict__ s1, const float* __restrict__ q1,
                          const float* __restrict__ g2, const float* __restrict__ b2,
                          const float* __restrict__ s2, const float* __restrict__ q2,
                          float* __restrict__ x2r, ushort_t* __restrict__ x2b,
                          uchar_t* __restrict__ x28){
    int i = blockIdx.x*256 + threadIdx.x;
    if (i >= NN*128) return;
    int n = i >> 7, c = i & 127;
    float m2 = s2[c] * INV_N;
    float v2 = q2[c] * INV_N - m2*m2;
    float rsv2 = rsqrtf(fmaxf(v2, 0.f) + BN_EPS);
    float val = bn_leaky(h2[i], m2, rsv2, g2[c], b2[c]);
    if (c < 64){
        float m1 = s1[c] * INV_N;
        float v1 = q1[c] * INV_N - m1*m1;
        float rsv1 = rsqrtf(fmaxf(v1, 0.f) + BN_EPS);
        val += bn_leaky(h1pre[(size_t)n*64 + c], m1, rsv1, g1[c], b1[c]) + nf[(size_t)n*64 + c];
    }
    if (c < 32) x2r[(size_t)n*32 + c] = val;
    x2b[i] = f2bf(val);
    int p = __builtin_amdgcn_cvt_pk_fp8_f32(val, val, 0, false);
    x28[i] = (uchar_t)(p & 0xFF);
}

// bn3 finals reduced inline from 4 hot-L2 partial groups
__global__ void bn_apply3(const float* __restrict__ h3, const float* __restrict__ x2r,
                          const float* __restrict__ g, const float* __restrict__ b,
                          const float* __restrict__ part3,
                          float* __restrict__ out){
    int i = blockIdx.x*256 + threadIdx.x;
    if (i >= NN*32) return;
    int c = i & 31;
    float s = 0.f, q = 0.f;
#pragma unroll
    for (int gg = 0; gg < 4; ++gg){
        s += part3[gg*64 + c];
        q += part3[gg*64 + 32 + c];
    }
    float m = s * INV_N;
    float v = q * INV_N - m*m;
    float rsv = rsqrtf(fmaxf(v, 0.f) + BN_EPS);
    out[i] = bn_leaky(h3[i], m, rsv, g[c], b[c]) + x2r[i];
}

// ---------------------------------------------------------------------------
// Attention: wave per dst node, CSR prefetch, 4 edges per half-wave in
// flight. k AND v gathered as fp8 (4 B/lane each) — 256 B/edge.
// Writes h2 = sb (skip) + attention output + bn2 stats into hierarchical
// partials (64 groups -> ~195 serial atomics/address).
// ---------------------------------------------------------------------------
__global__ __launch_bounds__(256) void attn_kernel(const ushort_t* __restrict__ qb,
                                                   const uchar_t* __restrict__ kb8,
                                                   const uchar_t* __restrict__ vb8,
                                                   const ushort_t* __restrict__ sb,
                                                   const int* __restrict__ rs,
                                                   const int* __restrict__ csr,
                                                   float* __restrict__ h2,
                                                   float* __restrict__ part2){
    __shared__ float sm[2][4][128];
    int w = threadIdx.x >> 6, lane = threadIdx.x & 63;
    int n = blockIdx.x*4 + w;                    // grid 12500*4 == 50000 exactly
    int half = lane >> 5, l5 = lane & 31;
    int e0 = rs[n*8], e1 = rs[n*8 + 8];
    int deg = e1 - e0;
    uint2 qu = *(const uint2*)(qb + (size_t)n*128 + l5*4);
    uint2 sbv = *(const uint2*)(sb + (size_t)n*128 + l5*4);
    float q0 = bflo(qu.x), q1 = bfhi(qu.x), q2 = bflo(qu.y), q3 = bfhi(qu.y);
    const float scale = 0.17677669529663687f;   // 1/sqrt(32)
    int idx = 0;
    if (lane < deg) idx = csr[e0 + lane];
    int dcap = min(deg, 64);
    int nt = (dcap + 7) >> 3;
    float den = 0.f, a0 = 0.f, a1 = 0.f, a2 = 0.f, a3 = 0.f;
    for (int t = 0; t < nt; ++t){
        int i2 = t*8 + half*4;
        int j0 = i2, j1 = i2+1, j2 = i2+2, j3 = i2+3;
        bool v0 = j0 < dcap, v1 = j1 < dcap, v2 = j2 < dcap, v3 = j3 < dcap;
        int s0 = __shfl(idx, j0 & 63); s0 = v0 ? s0 : 0;
        int s1 = __shfl(idx, j1 & 63); s1 = v1 ? s1 : 0;
        int s2 = __shfl(idx, j2 & 63); s2 = v2 ? s2 : 0;
        int s3 = __shfl(idx, j3 & 63); s3 = v3 ? s3 : 0;
        unsigned int ku0 = *(const unsigned int*)(kb8 + (size_t)s0*128 + l5*4);
        unsigned int ku1 = *(const unsigned int*)(kb8 + (size_t)s1*128 + l5*4);
        unsigned int ku2 = *(const unsigned int*)(kb8 + (size_t)s2*128 + l5*4);
        unsigned int ku3 = *(const unsigned int*)(kb8 + (size_t)s3*128 + l5*4);
        unsigned int vu0 = *(const unsigned int*)(vb8 + (size_t)s0*128 + l5*4);
        unsigned int vu1 = *(const unsigned int*)(vb8 + (size_t)s1*128 + l5*4);
        unsigned int vu2 = *(const unsigned int*)(vb8 + (size_t)s2*128 + l5*4);
        unsigned int vu3 = *(const unsigned int*)(vb8 + (size_t)s3*128 + l5*4);
        float ka, kb_, kc, kd;
        fp8_to_f4(ku0, ka, kb_, kc, kd);
        float p0 = q0*ka + q1*kb_ + q2*kc + q3*kd;
        fp8_to_f4(ku1, ka, kb_, kc, kd);
        float p1 = q0*ka + q1*kb_ + q2*kc + q3*kd;
        fp8_to_f4(ku2, ka, kb_, kc, kd);
        float p2 = q0*ka + q1*kb_ + q2*kc + q3*kd;
        fp8_to_f4(ku3, ka, kb_, kc, kd);
        float p3 = q0*ka + q1*kb_ + q2*kc + q3*kd;
        p0 += __shfl_xor(p0, 1); p1 += __shfl_xor(p1, 1); p2 += __shfl_xor(p2, 1); p3 += __shfl_xor(p3, 1);
        p0 += __shfl_xor(p0, 2); p1 += __shfl_xor(p1, 2); p2 += __shfl_xor(p2, 2); p3 += __shfl_xor(p3, 2);
        p0 += __shfl_xor(p0, 4); p1 += __shfl_xor(p1, 4); p2 += __shfl_xor(p2, 4); p3 += __shfl_xor(p3, 4);
        float w0 = v0 ? __expf(p0 * scale) : 0.f;
        float w1 = v1 ? __expf(p1 * scale) : 0.f;
        float w2 = v2 ? __expf(p2 * scale) : 0.f;
        float w3 = v3 ? __expf(p3 * scale) : 0.f;
        den += w0 + w1 + w2 + w3;
        float va, vb_, vc, vd;
        fp8_to_f4(vu0, va, vb_, vc, vd);
        a0 = fmaf(w0, va, a0); a1 = fmaf(w0, vb_, a1); a2 = fmaf(w0, vc, a2); a3 = fmaf(w0, vd, a3);
        fp8_to_f4(vu1, va, vb_, vc, vd);
        a0 = fmaf(w1, va, a0); a1 = fmaf(w1, vb_, a1); a2 = fmaf(w1, vc, a2); a3 = fmaf(w1, vd, a3);
        fp8_to_f4(vu2, va, vb_, vc, vd);
        a0 = fmaf(w2, va, a0); a1 = fmaf(w2, vb_, a1); a2 = fmaf(w2, vc, a2); a3 = fmaf(w2, vd, a3);
        fp8_to_f4(vu3, va, vb_, vc, vd);
        a0 = fmaf(w3, va, a0); a1 = fmaf(w3, vb_, a1); a2 = fmaf(w3, vc, a2); a3 = fmaf(w3, vd, a3);
    }
    // tail: deg > 64 (rare). Half-uniform trip counts; shuffles stay in-half.
    for (int e = 64 + half; e < deg; e += 2){
        int s = csr[e0 + e];
        unsigned int ku = *(const unsigned int*)(kb8 + (size_t)s*128 + l5*4);
        unsigned int vu = *(const unsigned int*)(vb8 + (size_t)s*128 + l5*4);
        float ka, kb_, kc, kd;
        fp8_to_f4(ku, ka, kb_, kc, kd);
        float p = q0*ka + q1*kb_ + q2*kc + q3*kd;
        p += __shfl_xor(p, 1);
        p += __shfl_xor(p, 2);
        p += __shfl_xor(p, 4);
        float wg = __expf(p * scale);
        den += wg;
        float va, vb_, vc, vd;
        fp8_to_f4(vu, va, vb_, vc, vd);
        a0 = fmaf(wg, va, a0); a1 = fmaf(wg, vb_, a1); a2 = fmaf(wg, vc, a2); a3 = fmaf(wg, vd, a3);
    }
    den += __shfl_xor(den, 32);
    a0 += __shfl_xor(a0, 32); a1 += __shfl_xor(a1, 32);
    a2 += __shfl_xor(a2, 32); a3 += __shfl_xor(a3, 32);
    float inv = (den > 0.f) ? 1.f/den : 0.f;
    float o0 = bflo(sbv.x) + a0*inv;
    float o1 = bfhi(sbv.x) + a1*inv;
    float o2 = bflo(sbv.y) + a2*inv;
    float o3 = bfhi(sbv.y) + a3*inv;
    if (half == 0){
        float4 o; o.x = o0; o.y = o1; o.z = o2; o.w = o3;
        *(float4*)(h2 + (size_t)n*128 + l5*4) = o;
        float4 t; t.x = o0; t.y = o1; t.z = o2; t.w = o3;
        *(float4*)&sm[0][w][l5*4] = t;
    } else {
        float4 t; t.x = o0*o0; t.y = o1*o1; t.z = o2*o2; t.w = o3*o3;
        *(float4*)&sm[1][w][l5*4] = t;
    }
    __syncthreads();
    // fused bn2 stats -> hierarchical partial group (blockIdx & 63)
    {
        int t = threadIdx.x;
        int st = t >> 7, c = t & 127;
        float v = sm[st][0][c] + sm[st][1][c] + sm[st][2][c] + sm[st][3][c];
        atomicAdd(&part2[(blockIdx.x & 63)*256 + st*128 + c], v);
    }
}

// ---------------------------------------------------------------------------
// SAGE mean aggregation: CSR prefetch, 4 edges/half, fp8 gathers (4 B/lane)
// ---------------------------------------------------------------------------
__global__ __launch_bounds__(256) void sage_agg(const uchar_t* __restrict__ x28,
                                                const int* __restrict__ rs,
                                                const int* __restrict__ csr,
                                                ushort_t* __restrict__ nmeanb){
    int w = threadIdx.x >> 6, lane = threadIdx.x & 63;
    int n = blockIdx.x*4 + w;
    if (n >= NN) return;
    int half = lane >> 5, l5 = lane & 31;
    int e0 = rs[n*8], e1 = rs[n*8 + 8];
    int deg = e1 - e0;
    int idx = 0;
    if (lane < deg) idx = csr[e0 + lane];
    int dcap = min(deg, 64);
    int nt = (dcap + 7) >> 3;
    f32x2 A0 = {0.f,0.f}, A1 = {0.f,0.f};
    for (int t = 0; t < nt; ++t){
        int i2 = t*8 + half*4;
        int j0 = i2, j1 = i2+1, j2 = i2+2, j3 = i2+3;
        bool v0 = j0 < dcap, v1 = j1 < dcap, v2 = j2 < dcap, v3 = j3 < dcap;
        int s0 = __shfl(idx, j0 & 63); s0 = v0 ? s0 : 0;
        int s1 = __shfl(idx, j1 & 63); s1 = v1 ? s1 : 0;
        int s2 = __shfl(idx, j2 & 63); s2 = v2 ? s2 : 0;
        int s3 = __shfl(idx, j3 & 63); s3 = v3 ? s3 : 0;
        unsigned int u0 = *(const unsigned int*)(x28 + (size_t)s0*128 + l5*4);
        unsigned int u1 = *(const unsigned int*)(x28 + (size_t)s1*128 + l5*4);
        unsigned int u2 = *(const unsigned int*)(x28 + (size_t)s2*128 + l5*4);
        unsigned int u3 = *(const unsigned int*)(x28 + (size_t)s3*128 + l5*4);
        u0 = v0 ? u0 : 0u; u1 = v1 ? u1 : 0u;
        u2 = v2 ? u2 : 0u; u3 = v3 ? u3 : 0u;
        A0 += __builtin_amdgcn_cvt_pk_f32_fp8(u0, false);
        A1 += __builtin_amdgcn_cvt_pk_f32_fp8(u0, true);
        A0 += __builtin_amdgcn_cvt_pk_f32_fp8(u1, false);
        A1 += __builtin_amdgcn_cvt_pk_f32_fp8(u1, true);
        A0 += __builtin_amdgcn_cvt_pk_f32_fp8(u2, false);
        A1 += __builtin_amdgcn_cvt_pk_f32_fp8(u2, true);
        A0 += __builtin_amdgcn_cvt_pk_f32_fp8(u3, false);
        A1 += __builtin_amdgcn_cvt_pk_f32_fp8(u3, true);
    }
    for (int e = 64 + half; e < deg; e += 2){
        int s = csr[e0 + e];
        unsigned int u = *(const unsigned int*)(x28 + (size_t)s*128 + l5*4);
        A0 += __builtin_amdgcn_cvt_pk_f32_fp8(u, false);
        A1 += __builtin_amdgcn_cvt_pk_f32_fp8(u, true);
    }
    float a0 = A0.x, a1 = A0.y, a2 = A1.x, a3 = A1.y;
    a0 += __shfl_xor(a0, 32); a1 += __shfl_xor(a1, 32);
    a2 += __shfl_xor(a2, 32); a3 += __shfl_xor(a3, 32);
    if (half == 0){
        float inv = 1.f / fmaxf((float)deg, 1.f);
        ushort4 o;
        o.x = f2bf(a0*inv); o.y = f2bf(a1*inv); o.z = f2bf(a2*inv); o.w = f2bf(a3*inv);
        *(ushort4*)(nmeanb + (size_t)n*128 + l5*4) = o;
    }
}

// ---------------------------------------------------------------------------
extern "C" void kernel_launch(void* const* d_in, const int* in_sizes, int n_in,
                              void* d_out, int out_size, void* d_ws, size_t ws_size,
                              hipStream_t stream){
    const float* nf      = (const float*)d_in[0];
    const int*   ei      = (const int*)d_in[2];
    const int*   et      = (const int*)d_in[3];
    const float* rgcn_w  = (const float*)d_in[4];
    const float* root    = (const float*)d_in[5];
    const float* rbias   = (const float*)d_in[6];
    const float* bn1g    = (const float*)d_in[7];
    const float* bn1b    = (const float*)d_in[8];
    const float* wq      = (const float*)d_in[9];
    const float* bq      = (const float*)d_in[10];
    const float* wk      = (const float*)d_in[11];
    const float* bk      = (const float*)d_in[12];
    const float* wv      = (const float*)d_in[13];
    const float* bv      = (const float*)d_in[14];
    const float* wsk     = (const float*)d_in[15];
    const float* bsk     = (const float*)d_in[16];
    const float* bn2g    = (const float*)d_in[17];
    const float* bn2b    = (const float*)d_in[18];
    const float* wl      = (const float*)d_in[19];
    const float* bl      = (const float*)d_in[20];
    const float* wr      = (const float*)d_in[21];
    const float* bn3g    = (const float*)d_in[22];
    const float* bn3b    = (const float*)d_in[23];
    float* out = (float*)d_out;

    // ---- workspace carve (256B aligned) ----
    char* base = (char*)d_ws;
    size_t off = 0;
    auto take = [&](size_t bytes) -> char* {
        char* p = base + off;
        off += (bytes + 255) & ~(size_t)255;
        return p;
    };
    int*      deg    = (int*)take((size_t)NR*4);
    float*    bns    = (float*)take(1024*4);
    float*    part1  = (float*)take(32*128*4);              // bn1 partials (16 KB)
    float*    part2  = (float*)take(64*256*4);              // bn2 partials (64 KB)
    float*    part3  = (float*)take(4*64*4);                // bn3 partials (1 KB)
    char*     zend   = base + off;                     // zero [deg, zend) in one memset
    int*      rs     = (int*)take((size_t)(NR+1)*4);
    int*      tmp    = (int*)take((size_t)NR*4);
    int*      bsum   = (int*)take(1024*4);
    uint2*    sr     = (uint2*)take((size_t)NE*8);          // (seg, rank) per edge (6.4 MB)
    int*      csr    = (int*)take((size_t)NE*4);
    ushort_t* Wcat   = (ushort_t*)take(64*576*2);
    ushort_t* Wt2    = (ushort_t*)take(512*64*2);
    float*    bcat   = (float*)take(512*4);
    ushort_t* Wsage  = (ushort_t*)take(32*256*2);
    ushort_t* xb     = (ushort_t*)take((size_t)NN*64*2);
    uchar_t*  xb8    = (uchar_t*)take((size_t)NN*64);       // fp8 gather copy (3.2 MB)
    float*    h1pre  = (float*)take((size_t)NN*64*4);
    float*    h2     = (float*)take((size_t)NN*128*4);
    float*    x2r    = (float*)take((size_t)NN*32*4);
    ushort_t* sb     = (ushort_t*)take((size_t)NN*128*2);   // bf16 skip (12.8 MB)
    char*     bigA   = take((size_t)NN*512*2);              // 51.2 MB multi-use
    if (off > ws_size) return;

    // bigA aliases (byte offsets); lifetimes verified stage-by-stage:
    ushort_t* qb     = (ushort_t*)(bigA + (size_t)NN*128);       // gemm_qkvs -> attn (12.8 MB)
    uchar_t*  vb8    = (uchar_t*)(bigA + (size_t)NN*384);        // gemm_qkvs -> attn (6.4 MB)
    uchar_t*  kb8    = (uchar_t*)(bigA + (size_t)NN*640);        // gemm_qkvs -> attn (6.4 MB)
    ushort_t* x2b    = (ushort_t*)bigA;                          // bn_apply2 -> sage_gemm (12.8 MB)
    uchar_t*  x28    = (uchar_t*)(bigA + (size_t)NN*256);        // bn_apply2 -> sage_agg (6.4 MB)
    ushort_t* nmeanb = (ushort_t*)(bigA + (size_t)NN*512);       // sage_agg -> sage_gemm (12.8 MB)
    float*    h3     = (float*)(bigA + (size_t)NN*768);          // sage_gemm -> bn3 (6.4 MB)

    hipMemsetAsync(deg, 0, (size_t)(zend - (char*)deg), stream); // deg + bns + partials

    // ---- CSR build (relation-bucketed, atomic-free fill) + weight prep ----
    const int PREP_N = NN*16 + 64*576 + 512*64 + 512 + 32*256 + NE;
    k_prep <<<(PREP_N+255)/256, 256, 0, stream>>>(nf, rgcn_w, root, wq, wk, wv, wsk,
                                                  bq, bk, bv, bsk, wl, wr,
                                                  ei, et, deg, sr,
                                                  xb, xb8, Wcat, Wt2, bcat, Wsage);
    k_scan1<<<NB2, SCAN_BS, 0, stream>>>(deg, tmp, bsum);
    k_scan2<<<1, 1024, 0, stream>>>(bsum);
    k_scan3<<<(NR+255)/256, 256, 0, stream>>>(tmp, bsum, rs);
    k_fill <<<(NE+255)/256, 256, 0, stream>>>(ei, sr, rs, csr);

    const int NB4 = (NN + 3) / 4;
    const int NBG = (NN + 63) / 64;

    // ---- stage 1: RGCN (fused agg + MFMA + bn1 partial stats) ----
    rgcn_fused<<<NN/16, 256, 0, stream>>>(xb, xb8, rs, csr, Wcat, rbias, h1pre, part1);

    // ---- stage 2: TransformerConv ----
    gemm_qkvs<<<NBG, 256, 0, stream>>>(h1pre, nf, part1, bn1g, bn1b,
                                       Wt2, bcat, qb, kb8, vb8, sb);
    attn_kernel<<<NB4, 256, 0, stream>>>(qb, kb8, vb8, sb, rs, csr, h2, part2);
    k_red2<<<1, 256, 0, stream>>>(part1, part2, bns);
    bn_apply2<<<(NN*128+255)/256, 256, 0, stream>>>(h2, h1pre, nf,
                                                    bn1g, bn1b, bns + 0, bns + 64,
                                                    bn2g, bn2b, bns + 128, bns + 256,
                                                    x2r, x2b, x28);

    // ---- stage 3: SAGE ----
    sage_agg<<<NB4, 256, 0, stream>>>(x28, rs, csr, nmeanb);
    sage_gemm<<<NBG, 256, 0, stream>>>(x2b, nmeanb, Wsage, bl, h3, part3);
    bn_apply3<<<(NN*32+255)/256, 256, 0, stream>>>(h3, x2r, bn3g, bn3b, part3, out);
}

// Round 9
// 363.437 us; speedup vs baseline: 1.1207x; 1.0059x over previous
//
#include <hip/hip_runtime.h>
#include <stdint.h>

#define NN 50000
#define NE 800000
#define NE4 (NE/4)           // edge threads in k_prep (4 edges each)
#define NR (NN*8)            // (node, relation) segments
#define SCAN_BS 512
#define NB2 782              // ceil(NR/512)
#define INV_N (1.0f/50000.0f)
#define BN_EPS 1e-5f

typedef unsigned short ushort_t;
typedef unsigned char uchar_t;
typedef short bf16x8 __attribute__((ext_vector_type(8)));   // 8 bf16 (4 VGPRs)
typedef float f32x4 __attribute__((ext_vector_type(4)));
typedef float f32x2 __attribute__((ext_vector_type(2)));

__device__ __forceinline__ ushort_t f2bf(float f){
    unsigned int u = __float_as_uint(f);
    u += 0x7FFFu + ((u >> 16) & 1u);      // RNE
    return (ushort_t)(u >> 16);
}
__device__ __forceinline__ float bf2f(ushort_t h){ return __uint_as_float(((unsigned int)h) << 16); }
__device__ __forceinline__ float bflo(unsigned int u){ return __uint_as_float(u << 16); }
__device__ __forceinline__ float bfhi(unsigned int u){ return __uint_as_float(u & 0xFFFF0000u); }

// fp8 e4m3 (OCP) helpers via HW converters
__device__ __forceinline__ unsigned int f4_to_fp8(float a, float b, float c, float d){
    int v = __builtin_amdgcn_cvt_pk_fp8_f32(a, b, 0, false);
    v = __builtin_amdgcn_cvt_pk_fp8_f32(c, d, v, true);
    return (unsigned int)v;
}
__device__ __forceinline__ void fp8_to_f4(unsigned int u, float& a, float& b, float& c, float& d){
    f32x2 lo = __builtin_amdgcn_cvt_pk_f32_fp8(u, false);
    f32x2 hi = __builtin_amdgcn_cvt_pk_f32_fp8(u, true);
    a = lo.x; b = lo.y; c = hi.x; d = hi.y;
}

// ---------------------------------------------------------------------------
// Prep (merged with k_deg). EDGE THREADS FIRST (4 edges each, int4 loads,
// 4 independent return-atomics in flight/lane) so the atomic-latency pass
// overlaps the node-cast/weight BW work that follows in the grid.
// ---------------------------------------------------------------------------
__global__ void k_prep(const float* __restrict__ nf,
                       const float* __restrict__ rgcn_w, const float* __restrict__ root,
                       const float* __restrict__ wq, const float* __restrict__ wk,
                       const float* __restrict__ wv, const float* __restrict__ wsk,
                       const float* __restrict__ bq, const float* __restrict__ bk,
                       const float* __restrict__ bv, const float* __restrict__ bsk,
                       const float* __restrict__ wl, const float* __restrict__ wr,
                       const int* __restrict__ ei, const int* __restrict__ et,
                       int* __restrict__ deg, uint2* __restrict__ sr,
                       ushort_t* __restrict__ xb, uchar_t* __restrict__ xb8,
                       ushort_t* __restrict__ Wcat,
                       ushort_t* __restrict__ Wt2, float* __restrict__ bcat,
                       ushort_t* __restrict__ Wsage){
    int i = blockIdx.x*256 + threadIdx.x;
    if (i < NE4){
        int4 d = ((const int4*)(ei + NE))[i];
        int4 r = ((const int4*)et)[i];
        int s0 = d.x*8 + r.x, s1 = d.y*8 + r.y;
        int s2 = d.z*8 + r.z, s3 = d.w*8 + r.w;
        int r0 = atomicAdd(&deg[s0], 1);
        int r1 = atomicAdd(&deg[s1], 1);
        int r2 = atomicAdd(&deg[s2], 1);
        int r3 = atomicAdd(&deg[s3], 1);
        uint2* o = sr + (size_t)i*4;
        uint2 o0; o0.x = (unsigned)s0; o0.y = (unsigned)r0; o[0] = o0;
        uint2 o1; o1.x = (unsigned)s1; o1.y = (unsigned)r1; o[1] = o1;
        uint2 o2; o2.x = (unsigned)s2; o2.y = (unsigned)r2; o[2] = o2;
        uint2 o3; o3.x = (unsigned)s3; o3.y = (unsigned)r3; o[3] = o3;
        return;
    }
    int ii = i - NE4;
    const int NXB = NN*16;
    if (ii < NXB){
        float4 v = ((const float4*)nf)[ii];
        ushort4 h;
        h.x = f2bf(v.x); h.y = f2bf(v.y); h.z = f2bf(v.z); h.w = f2bf(v.w);
        ((ushort4*)xb)[ii] = h;
        ((unsigned int*)xb8)[ii] = f4_to_fp8(v.x, v.y, v.z, v.w);
        return;
    }
    int j = ii - NXB;
    if (j < 64*576){
        int h = j / 576, k = j - h*576;
        float v = (k < 512) ? rgcn_w[(size_t)k*64 + h] : root[(size_t)(k-512)*64 + h];
        Wcat[j] = f2bf(v);
    } else if (j < 64*576 + 512*64){
        int jj = j - 64*576;
        int c = jj >> 6, k = jj & 63;
        int mt = c >> 7, cc = c & 127;
        const float* W = (mt==0)?wq:(mt==1)?wk:(mt==2)?wv:wsk;
        Wt2[jj] = f2bf(W[(size_t)k*128 + cc]);
    } else if (j < 64*576 + 512*64 + 512){
        int c = j - (64*576 + 512*64);
        int mt = c >> 7, cc = c & 127;
        const float* B = (mt==0)?bq:(mt==1)?bk:(mt==2)?bv:bsk;
        bcat[c] = B[cc];
    } else if (j < 64*576 + 512*64 + 512 + 32*256){
        int jj = j - (64*576 + 512*64 + 512);
        int c = jj >> 8, k = jj & 255;
        float v = (k < 128) ? wr[(size_t)k*32 + c] : wl[(size_t)(k-128)*32 + c];
        Wsage[jj] = f2bf(v);
    }
}

__global__ void k_scan1(const int* __restrict__ deg, int* __restrict__ tmp, int* __restrict__ bsum){
    __shared__ int s[SCAN_BS];
    int t = threadIdx.x;
    int i = blockIdx.x*SCAN_BS + t;
    s[t] = (i < NR) ? deg[i] : 0;
    __syncthreads();
    for (int off = 1; off < SCAN_BS; off <<= 1){
        int add = (t >= off) ? s[t-off] : 0;
        __syncthreads();
        s[t] += add;
        __syncthreads();
    }
    if (i < NR) tmp[i] = s[t];
    if (t == SCAN_BS-1) bsum[blockIdx.x] = s[t];
}

// parallel Hillis-Steele over 1024 slots (NB2=782 live)
__global__ void k_scan2(int* __restrict__ bsum){
    __shared__ int s[1024];
    int t = threadIdx.x;
    s[t] = (t < NB2) ? bsum[t] : 0;
    __syncthreads();
    for (int off = 1; off < 1024; off <<= 1){
        int v = (t >= off) ? s[t-off] : 0;
        __syncthreads();
        s[t] += v;
        __syncthreads();
    }
    if (t < NB2) bsum[t] = s[t];
}

__global__ void k_scan3(const int* __restrict__ tmp, const int* __restrict__ bsum, int* __restrict__ rs){
    int i = blockIdx.x*256 + threadIdx.x;
    if (i < NR){
        int b = i >> 9;
        int off = (b > 0) ? bsum[b-1] : 0;
        rs[i+1] = tmp[i] + off;
        if (i == 0) rs[0] = 0;
    }
}

// atomic-free: pos = rs[seg] + rank (deterministic given captured ranks)
__global__ void k_fill(const int* __restrict__ ei, const uint2* __restrict__ sr,
                       const int* __restrict__ rs, int* __restrict__ csr){
    int e = blockIdx.x*256 + threadIdx.x;
    if (e < NE){
        uint2 s = sr[e];
        csr[rs[s.x] + (int)s.y] = ei[e];
    }
}

// ---------------------------------------------------------------------------
// FUSED RGCN. Phase 1: quad owns ADJACENT relations {2q, 2q+1} and walks
// their CONCATENATED csr range as one run of la+lb edges (4 loads/lane/trip).
// Phase 2: 16x64 MFMA, K=576. Epilogue: h1pre + bn1 partial stats.
// ---------------------------------------------------------------------------
__global__ __launch_bounds__(256) void rgcn_fused(const ushort_t* __restrict__ xb,
                                                  const uchar_t* __restrict__ xb8,
                                                  const int* __restrict__ rs,
                                                  const int* __restrict__ csr,
                                                  const ushort_t* __restrict__ Wcat,
                                                  const float* __restrict__ bias,
                                                  float* __restrict__ h1pre,
                                                  float* __restrict__ part1){
    __shared__ ushort_t Ml[16*520];
    int w = threadIdx.x >> 6, lane = threadIdx.x & 63;
    int quad = lane >> 4, l4 = lane & 15;
    int row0 = blockIdx.x * 16;                 // 3125*16 == 50000 exactly
    int n0 = row0 + w*4;
    int rsel = (lane < 9 ? lane : 8);
    int rb = rs[n0*8 + rsel];
    int eb0 = __shfl(rb, 0);
    int dg0 = __shfl(rb, 8) - eb0;
    int idx = (lane < dg0) ? csr[eb0 + lane] : 0;
    for (int j = 0; j < 4; ++j){
        int lrow = (w*4 + j)*520;
        int ebase = __shfl(rb, 0);
        int enext = __shfl(rb, 8);
        int rb_next = 0, idxn = 0;
        if (j < 3){
            rb_next = rs[(n0 + j + 1)*8 + rsel];
            idxn = csr[min(enext + lane, NE - 1)];   // addr independent of rb_next
        }
        int e0a = __shfl(rb, 2*quad);
        int e1a = __shfl(rb, 2*quad + 1);
        int e2a = __shfl(rb, 2*quad + 2);
        int oa = e0a - ebase;                  // combined-range start offset
        int la = e1a - e0a, lb = e2a - e1a;
        int tot = la + lb;
        int fastN = min(tot, max(64 - oa, 0)); // slots resident in idx window
        int ml = fastN;
        ml = max(ml, __shfl_xor(ml, 16));
        ml = max(ml, __shfl_xor(ml, 32));
        f32x2 aA0 = {0.f,0.f}, aA1 = {0.f,0.f};
        f32x2 aB0 = {0.f,0.f}, aB1 = {0.f,0.f};
        for (int i = 0; i < ml; i += 4){
            unsigned int uX[4];
#pragma unroll
            for (int u = 0; u < 4; ++u){
                int jj = i + u;
                int t = __shfl(idx, (oa + jj) & 63);
                t = (jj < fastN) ? t : 0;            // row 0: L1-hot dummy
                uX[u] = *(const unsigned int*)(xb8 + (size_t)t*64 + l4*4);
            }
#pragma unroll
            for (int u = 0; u < 4; ++u){
                int jj = i + u;
                unsigned int a = (jj < fastN) ? uX[u] : 0u;   // fp8 0x00 == 0.0f
                f32x2 lo = __builtin_amdgcn_cvt_pk_f32_fp8(a, false);
                f32x2 hi = __builtin_amdgcn_cvt_pk_f32_fp8(a, true);
                if (jj < la){ aA0 += lo; aA1 += hi; }          // quad-uniform split
                else        { aB0 += lo; aB1 += hi; }
            }
        }
        // rare tails: combined slots past the 64-entry idx window
        for (int jj = min(la, fastN); jj < la; ++jj){
            int t = csr[e0a + jj];
            unsigned int a = *(const unsigned int*)(xb8 + (size_t)t*64 + l4*4);
            aA0 += __builtin_amdgcn_cvt_pk_f32_fp8(a, false);
            aA1 += __builtin_amdgcn_cvt_pk_f32_fp8(a, true);
        }
        for (int jj = max(la, fastN); jj < tot; ++jj){
            int t = csr[e0a + jj];
            unsigned int b = *(const unsigned int*)(xb8 + (size_t)t*64 + l4*4);
            aB0 += __builtin_amdgcn_cvt_pk_f32_fp8(b, false);
            aB1 += __builtin_amdgcn_cvt_pk_f32_fp8(b, true);
        }
        float inva = 1.f / fmaxf((float)la, 1.f);
        float invb = 1.f / fmaxf((float)lb, 1.f);
        ushort4 oA, oB;
        oA.x = f2bf(aA0.x*inva); oA.y = f2bf(aA0.y*inva); oA.z = f2bf(aA1.x*inva); oA.w = f2bf(aA1.y*inva);
        oB.x = f2bf(aB0.x*invb); oB.y = f2bf(aB0.y*invb); oB.z = f2bf(aB1.x*invb); oB.w = f2bf(aB1.y*invb);
        *(ushort4*)&Ml[lrow + (2*quad)*64 + l4*4] = oA;
        *(ushort4*)&Ml[lrow + (2*quad + 1)*64 + l4*4] = oB;
        if (j < 3){
            rb = rb_next;
            int ebn = __shfl(rb, 0);
            int dgn = __shfl(rb, 8) - ebn;
            idx = (lane < dgn) ? idxn : 0;
        }
    }
    __syncthreads();
    int m = l4;
    f32x4 acc = {};
#pragma unroll
    for (int kt = 0; kt < 18; ++kt){
        int kk = kt*32 + quad*8;
        bf16x8 a;
        if (kt < 16) a = *(const bf16x8*)&Ml[m*520 + kk];
        else         a = *(const bf16x8*)(xb + (size_t)(row0 + m)*64 + (kk - 512));
        bf16x8 b = *(const bf16x8*)(Wcat + (size_t)(w*16 + m)*576 + kk);
        acc = __builtin_amdgcn_mfma_f32_16x16x32_bf16(a, b, acc, 0, 0, 0);
    }
    int col = w*16 + m;
    float bz = bias[col];
    float s = 0.f, q = 0.f;
#pragma unroll
    for (int i = 0; i < 4; ++i){
        int rr = row0 + quad*4 + i;
        float y = acc[i] + bz;
        h1pre[(size_t)rr*64 + col] = y;
        s += y; q += y*y;
    }
    s += __shfl_xor(s, 16); q += __shfl_xor(q, 16);
    s += __shfl_xor(s, 32); q += __shfl_xor(q, 32);
    if (quad == 0){
        float* pg = part1 + (blockIdx.x & 31)*128;
        atomicAdd(&pg[col], s);
        atomicAdd(&pg[64 + col], q);
    }
}

// ---------------------------------------------------------------------------
// MFMA GEMM 2 (both col-groups in ONE kernel): Wt2 tile staged per cg with
// barriers; bn1 partials reduced block-cooperatively into LDS (L2-hot);
// h1pre/nf read once. k AND v stored as fp8.
// ---------------------------------------------------------------------------
#define QS 132   // pl row stride (ushorts)
#define BS 68    // Bs row stride (ushorts): 2-way bank alias (free, m136)
__global__ __launch_bounds__(256) void gemm_qkvs(const float* __restrict__ h1pre,
                                                 const float* __restrict__ nf,
                                                 const float* __restrict__ part1,
                                                 const float* __restrict__ g1, const float* __restrict__ b1,
                                                 const ushort_t* __restrict__ Wt2,
                                                 const float* __restrict__ bcat,
                                                 ushort_t* __restrict__ qb,
                                                 uchar_t* __restrict__ kb8,
                                                 uchar_t* __restrict__ vb8,
                                                 ushort_t* __restrict__ sb){
    __shared__ ushort_t Bs[256*BS];
    __shared__ ushort_t pl[4][16*QS];
    __shared__ float sred[128];
    int w = threadIdx.x >> 6, lane = threadIdx.x & 63;
    int m = lane & 15, quad = lane >> 4;
    int r0 = blockIdx.x*64 + w*16;
    int row = r0 + m;
    // ---- reduce bn1 partials (32 groups x 128, L2-hot) ----
    {
        int t = threadIdx.x;
        if (t < 128){
            float acc = 0.f;
#pragma unroll
            for (int g = 0; g < 32; ++g) acc += part1[g*128 + t];
            sred[t] = acc;
        }
    }
    __syncthreads();
    // ---- prologue (once): x1 fragments = bf16(leaky(bn1(h)) + nf) ----
    bf16x8 afrag[2];
#pragma unroll
    for (int kt = 0; kt < 2; ++kt){
        int db = kt*32 + quad*8;
        bf16x8 f = (bf16x8){0,0,0,0,0,0,0,0};
        if (row < NN){
            float4 h0 = *(const float4*)(h1pre + (size_t)row*64 + db);
            float4 h1 = *(const float4*)(h1pre + (size_t)row*64 + db + 4);
            float4 n0 = *(const float4*)(nf + (size_t)row*64 + db);
            float4 n1 = *(const float4*)(nf + (size_t)row*64 + db + 4);
            float4 ga = *(const float4*)(g1 + db);
            float4 gb_ = *(const float4*)(g1 + db + 4);
            float4 ba = *(const float4*)(b1 + db);
            float4 bb_ = *(const float4*)(b1 + db + 4);
            float hh[8] = {h0.x,h0.y,h0.z,h0.w,h1.x,h1.y,h1.z,h1.w};
            float nn[8] = {n0.x,n0.y,n0.z,n0.w,n1.x,n1.y,n1.z,n1.w};
            float GG[8] = {ga.x,ga.y,ga.z,ga.w,gb_.x,gb_.y,gb_.z,gb_.w};
            float BB[8] = {ba.x,ba.y,ba.z,ba.w,bb_.x,bb_.y,bb_.z,bb_.w};
#pragma unroll
            for (int e = 0; e < 8; ++e){
                float mm = sred[db + e] * INV_N;
                float vv = sred[64 + db + e] * INV_N - mm*mm;
                float A = rsqrtf(fmaxf(vv, 0.f) + BN_EPS) * GG[e];
                float C = BB[e] - mm * A;
                float y = fmaf(hh[e], A, C);
                y = (y >= 0.f) ? y : 0.01f*y;
                f[e] = (short)f2bf(y + nn[e]);
            }
        }
        afrag[kt] = f;
    }
    for (int cg = 0; cg < 2; ++cg){
        __syncthreads();     // prior cg's Bs reads (and sred reads) complete
        // ---- stage Wt2 col-group tile: 256 rows x 64 ush = 2048 uint4 ----
        {
            int t = threadIdx.x;
            const ushort_t* wsrc = Wt2 + (size_t)cg*256*64;
#pragma unroll
            for (int u0 = 0; u0 < 8; ++u0){
                int u = u0*256 + t;
                int r = u >> 3, c8 = (u & 7)*8;
                *(uint4*)&Bs[r*BS + c8] = *(const uint4*)(wsrc + u*8);
            }
        }
        __syncthreads();
        f32x4 acc[16] = {};
#pragma unroll
        for (int kt = 0; kt < 2; ++kt){
            int kk = kt*32 + quad*8;
#pragma unroll
            for (int ct = 0; ct < 16; ++ct){
                bf16x8 b = *(const bf16x8*)&Bs[(size_t)(ct*16 + m)*BS + kk];
                acc[ct] = __builtin_amdgcn_mfma_f32_16x16x32_bf16(afrag[kt], b, acc[ct], 0, 0, 0);
            }
        }
        // ---- half 0 (ct 0..7): cg0 -> q (bf16), cg1 -> v (fp8) ----
#pragma unroll
        for (int ct = 0; ct < 8; ++ct){
            int g = cg*256 + ct*16 + m;
            float bz = bcat[g];
            int cc = g & 127;
#pragma unroll
            for (int i = 0; i < 4; ++i)
                pl[w][(quad*4 + i)*QS + cc] = f2bf(acc[ct][i] + bz);
        }
        if (cg == 0){
#pragma unroll
            for (int t = 0; t < 4; ++t){
                int u = t*64 + lane;
                int r = u >> 4, c = (u & 15)*8;
                int gr = r0 + r;
                if (gr < NN) *(uint4*)(qb + (size_t)gr*128 + c) = *(const uint4*)&pl[w][r*QS + c];
            }
        } else {
#pragma unroll
            for (int t = 0; t < 4; ++t){
                int u = t*64 + lane;
                int r = u >> 4, c = (u & 15)*8;
                int gr = r0 + r;
                if (gr < NN){
                    uint4 vv4 = *(const uint4*)&pl[w][r*QS + c];
                    uint2 o;
                    o.x = f4_to_fp8(bflo(vv4.x), bfhi(vv4.x), bflo(vv4.y), bfhi(vv4.y));
                    o.y = f4_to_fp8(bflo(vv4.z), bfhi(vv4.z), bflo(vv4.w), bfhi(vv4.w));
                    *(uint2*)(vb8 + (size_t)gr*128 + c) = o;
                }
            }
        }
        // ---- half 1 (ct 8..15): cg0 -> k (fp8), cg1 -> skip ----
#pragma unroll
        for (int ct = 8; ct < 16; ++ct){
            int g = cg*256 + ct*16 + m;
            float bz = bcat[g];
            int cc = g & 127;
#pragma unroll
            for (int i = 0; i < 4; ++i)
                pl[w][(quad*4 + i)*QS + cc] = f2bf(acc[ct][i] + bz);
        }
        if (cg == 0){
#pragma unroll
            for (int t = 0; t < 4; ++t){
                int u = t*64 + lane;
                int r = u >> 4, c = (u & 15)*8;
                int gr = r0 + r;
                if (gr < NN){
                    uint4 kk4 = *(const uint4*)&pl[w][r*QS + c];
                    uint2 o;
                    o.x = f4_to_fp8(bflo(kk4.x), bfhi(kk4.x), bflo(kk4.y), bfhi(kk4.y));
                    o.y = f4_to_fp8(bflo(kk4.z), bfhi(kk4.z), bflo(kk4.w), bfhi(kk4.w));
                    *(uint2*)(kb8 + (size_t)gr*128 + c) = o;
                }
            }
        } else {
#pragma unroll
            for (int t = 0; t < 4; ++t){
                int u = t*64 + lane;
                int r = u >> 4, c = (u & 15)*8;
                int gr = r0 + r;
                if (gr < NN) *(uint4*)(sb + (size_t)gr*128 + c) = *(const uint4*)&pl[w][r*QS + c];
            }
        }
    }
}

// reduce bn1 partials (32x128) -> bns[0..127]; bn2 partials (64x256) -> bns[128..383]
__global__ void k_red2(const float* __restrict__ part1, const float* __restrict__ part2,
                       float* __restrict__ bns){
    int t = threadIdx.x;   // 256
    float acc = 0.f;
    for (int g = 0; g < 64; ++g) acc += part2[g*256 + t];
    bns[128 + t] = acc;
    if (t < 128){
        float a1 = 0.f;
        for (int g = 0; g < 32; ++g) a1 += part1[g*128 + t];
        bns[t] = a1;
    }
}

// ---------------------------------------------------------------------------
// MFMA GEMM 3: h3 = [x2b | nmeanb](50000x256) @ Wsage^T + bl  (32 cols)
// + bn3 stats into hierarchical partials (4 groups -> ~196/address).
// ---------------------------------------------------------------------------
__global__ __launch_bounds__(256) void sage_gemm(const ushort_t* __restrict__ x2b,
                                                 const ushort_t* __restrict__ nmeanb,
                                                 const ushort_t* __restrict__ Wsage,
                                                 const float* __restrict__ bl,
                                                 float* __restrict__ h3,
                                                 float* __restrict__ part3){
    int wv = threadIdx.x >> 6, lane = threadIdx.x & 63;
    int r0 = blockIdx.x*64 + wv*16;
    int m = lane & 15, quad = lane >> 4;
    int row = r0 + m;
    f32x4 acc[2] = {};
#pragma unroll
    for (int kt = 0; kt < 8; ++kt){
        int kk = kt*32 + quad*8;
        bf16x8 a;
        if (row < NN){
            const ushort_t* ap = (kt < 4) ? (x2b + (size_t)row*128 + kk)
                                          : (nmeanb + (size_t)row*128 + (kk - 128));
            a = *(const bf16x8*)ap;
        } else {
            a = (bf16x8){0,0,0,0,0,0,0,0};
        }
#pragma unroll
        for (int ct = 0; ct < 2; ++ct){
            bf16x8 b = *(const bf16x8*)(Wsage + (size_t)(ct*16 + m)*256 + kk);
            acc[ct] = __builtin_amdgcn_mfma_f32_16x16x32_bf16(a, b, acc[ct], 0, 0, 0);
        }
    }
    float s[2] = {0.f, 0.f}, q[2] = {0.f, 0.f};
#pragma unroll
    for (int ct = 0; ct < 2; ++ct){
        int col = ct*16 + m;
        float bz = bl[col];
#pragma unroll
        for (int i = 0; i < 4; ++i){
            int rr = r0 + quad*4 + i;
            if (rr < NN){
                float y = acc[ct][i] + bz;
                h3[(size_t)rr*32 + col] = y;
                s[ct] += y; q[ct] += y*y;
            }
        }
    }
#pragma unroll
    for (int ct = 0; ct < 2; ++ct){
        s[ct] += __shfl_xor(s[ct], 16); q[ct] += __shfl_xor(q[ct], 16);
        s[ct] += __shfl_xor(s[ct], 32); q[ct] += __shfl_xor(q[ct], 32);
    }
    if (quad == 0){
        float* pg = part3 + (blockIdx.x & 3)*64;
#pragma unroll
        for (int ct = 0; ct < 2; ++ct){
            int col = ct*16 + m;
            atomicAdd(&pg[col], s[ct]);
            atomicAdd(&pg[32 + col], q[ct]);
        }
    }
}

__device__ __forceinline__ float bn_leaky(float z, float m, float rsv, float g, float b){
    float y = (z - m) * rsv * g + b;
    return y >= 0.f ? y : 0.01f * y;
}

// x2 = leaky(bn2(h2)) + (c<64 ? x1 : 0); -> bf16 x2b, fp8 x28, cols<32 fp32 x2r
__global__ void bn_apply2(const float* __restrict__ h2, const float* __restrict__ h1pre,
                          const float* __restrict__ nf,
                          const float* __restrict__ g1, const float* __restrict__ b1,
                          const float* __restrict__ s1, const float* __restrict__ q1,
                          const float* __restrict__ g2, const float* __restrict__ b2,
                          const float* __restrict__ s2, const float* __restrict__ q2,
                          float* __restrict__ x2r, ushort_t* __restrict__ x2b,
                          uchar_t* __restrict__ x28){
    int i = blockIdx.x*256 + threadIdx.x;
    if (i >= NN*128) return;
    int n = i >> 7, c = i & 127;
    float m2 = s2[c] * INV_N;
    float v2 = q2[c] * INV_N - m2*m2;
    float rsv2 = rsqrtf(fmaxf(v2, 0.f) + BN_EPS);
    float val = bn_leaky(h2[i], m2, rsv2, g2[c], b2[c]);
    if (c < 64){
        float m1 = s1[c] * INV_N;
        float v1 = q1[c] * INV_N - m1*m1;
        float rsv1 = rsqrtf(fmaxf(v1, 0.f) + BN_EPS);
        val += bn_leaky(h1pre[(size_t)n*64 + c], m1, rsv1, g1[c], b1[c]) + nf[(size_t)n*64 + c];
    }
    if (c < 32) x2r[(size_t)n*32 + c] = val;
    x2b[i] = f2bf(val);
    int p = __builtin_amdgcn_cvt_pk_fp8_f32(val, val, 0, false);
    x28[i] = (uchar_t)(p & 0xFF);
}

// bn3 finals reduced inline from 4 hot-L2 partial groups
__global__ void bn_apply3(const float* __restrict__ h3, const float* __restrict__ x2r,
                          const float* __restrict__ g, const float* __restrict__ b,
                          const float* __restrict__ part3,
                          float* __restrict__ out){
    int i = blockIdx.x*256 + threadIdx.x;
    if (i >= NN*32) return;
    int c = i & 31;
    float s = 0.f, q = 0.f;
#pragma unroll
    for (int gg = 0; gg < 4; ++gg){
        s += part3[gg*64 + c];
        q += part3[gg*64 + 32 + c];
    }
    float m = s * INV_N;
    float v = q * INV_N - m*m;
    float rsv = rsqrtf(fmaxf(v, 0.f) + BN_EPS);
    out[i] = bn_leaky(h3[i], m, rsv, g[c], b[c]) + x2r[i];
}

// ---------------------------------------------------------------------------
// Attention: wave per dst node, CSR prefetch, 4 edges per half-wave in
// flight. k AND v gathered as fp8 (4 B/lane each) — 256 B/edge.
// Writes h2 = sb (skip) + attention output + bn2 stats into hierarchical
// partials (64 groups -> ~195 serial atomics/address).
// ---------------------------------------------------------------------------
__global__ __launch_bounds__(256) void attn_kernel(const ushort_t* __restrict__ qb,
                                                   const uchar_t* __restrict__ kb8,
                                                   const uchar_t* __restrict__ vb8,
                                                   const ushort_t* __restrict__ sb,
                                                   const int* __restrict__ rs,
                                                   const int* __restrict__ csr,
                                                   float* __restrict__ h2,
                                                   float* __restrict__ part2){
    __shared__ float sm[2][4][128];
    int w = threadIdx.x >> 6, lane = threadIdx.x & 63;
    int n = blockIdx.x*4 + w;                    // grid 12500*4 == 50000 exactly
    int half = lane >> 5, l5 = lane & 31;
    int e0 = rs[n*8], e1 = rs[n*8 + 8];
    int deg = e1 - e0;
    uint2 qu = *(const uint2*)(qb + (size_t)n*128 + l5*4);
    uint2 sbv = *(const uint2*)(sb + (size_t)n*128 + l5*4);
    float q0 = bflo(qu.x), q1 = bfhi(qu.x), q2 = bflo(qu.y), q3 = bfhi(qu.y);
    const float scale = 0.17677669529663687f;   // 1/sqrt(32)
    int idx = 0;
    if (lane < deg) idx = csr[e0 + lane];
    int dcap = min(deg, 64);
    int nt = (dcap + 7) >> 3;
    float den = 0.f, a0 = 0.f, a1 = 0.f, a2 = 0.f, a3 = 0.f;
    for (int t = 0; t < nt; ++t){
        int i2 = t*8 + half*4;
        int j0 = i2, j1 = i2+1, j2 = i2+2, j3 = i2+3;
        bool v0 = j0 < dcap, v1 = j1 < dcap, v2 = j2 < dcap, v3 = j3 < dcap;
        int s0 = __shfl(idx, j0 & 63); s0 = v0 ? s0 : 0;
        int s1 = __shfl(idx, j1 & 63); s1 = v1 ? s1 : 0;
        int s2 = __shfl(idx, j2 & 63); s2 = v2 ? s2 : 0;
        int s3 = __shfl(idx, j3 & 63); s3 = v3 ? s3 : 0;
        unsigned int ku0 = *(const unsigned int*)(kb8 + (size_t)s0*128 + l5*4);
        unsigned int ku1 = *(const unsigned int*)(kb8 + (size_t)s1*128 + l5*4);
        unsigned int ku2 = *(const unsigned int*)(kb8 + (size_t)s2*128 + l5*4);
        unsigned int ku3 = *(const unsigned int*)(kb8 + (size_t)s3*128 + l5*4);
        unsigned int vu0 = *(const unsigned int*)(vb8 + (size_t)s0*128 + l5*4);
        unsigned int vu1 = *(const unsigned int*)(vb8 + (size_t)s1*128 + l5*4);
        unsigned int vu2 = *(const unsigned int*)(vb8 + (size_t)s2*128 + l5*4);
        unsigned int vu3 = *(const unsigned int*)(vb8 + (size_t)s3*128 + l5*4);
        float ka, kb_, kc, kd;
        fp8_to_f4(ku0, ka, kb_, kc, kd);
        float p0 = q0*ka + q1*kb_ + q2*kc + q3*kd;
        fp8_to_f4(ku1, ka, kb_, kc, kd);
        float p1 = q0*ka + q1*kb_ + q2*kc + q3*kd;
        fp8_to_f4(ku2, ka, kb_, kc, kd);
        float p2 = q0*ka + q1*kb_ + q2*kc + q3*kd;
        fp8_to_f4(ku3, ka, kb_, kc, kd);
        float p3 = q0*ka + q1*kb_ + q2*kc + q3*kd;
        p0 += __shfl_xor(p0, 1); p1 += __shfl_xor(p1, 1); p2 += __shfl_xor(p2, 1); p3 += __shfl_xor(p3, 1);
        p0 += __shfl_xor(p0, 2); p1 += __shfl_xor(p1, 2); p2 += __shfl_xor(p2, 2); p3 += __shfl_xor(p3, 2);
        p0 += __shfl_xor(p0, 4); p1 += __shfl_xor(p1, 4); p2 += __shfl_xor(p2, 4); p3 += __shfl_xor(p3, 4);
        float w0 = v0 ? __expf(p0 * scale) : 0.f;
        float w1 = v1 ? __expf(p1 * scale) : 0.f;
        float w2 = v2 ? __expf(p2 * scale) : 0.f;
        float w3 = v3 ? __expf(p3 * scale) : 0.f;
        den += w0 + w1 + w2 + w3;
        float va, vb_, vc, vd;
        fp8_to_f4(vu0, va, vb_, vc, vd);
        a0 = fmaf(w0, va, a0); a1 = fmaf(w0, vb_, a1); a2 = fmaf(w0, vc, a2); a3 = fmaf(w0, vd, a3);
        fp8_to_f4(vu1, va, vb_, vc, vd);
        a0 = fmaf(w1, va, a0); a1 = fmaf(w1, vb_, a1); a2 = fmaf(w1, vc, a2); a3 = fmaf(w1, vd, a3);
        fp8_to_f4(vu2, va, vb_, vc, vd);
        a0 = fmaf(w2, va, a0); a1 = fmaf(w2, vb_, a1); a2 = fmaf(w2, vc, a2); a3 = fmaf(w2, vd, a3);
        fp8_to_f4(vu3, va, vb_, vc, vd);
        a0 = fmaf(w3, va, a0); a1 = fmaf(w3, vb_, a1); a2 = fmaf(w3, vc, a2); a3 = fmaf(w3, vd, a3);
    }
    // tail: deg > 64 (rare). Half-uniform trip counts; shuffles stay in-half.
    for (int e = 64 + half; e < deg; e += 2){
        int s = csr[e0 + e];
        unsigned int ku = *(const unsigned int*)(kb8 + (size_t)s*128 + l5*4);
        unsigned int vu = *(const unsigned int*)(vb8 + (size_t)s*128 + l5*4);
        float ka, kb_, kc, kd;
        fp8_to_f4(ku, ka, kb_, kc, kd);
        float p = q0*ka + q1*kb_ + q2*kc + q3*kd;
        p += __shfl_xor(p, 1);
        p += __shfl_xor(p, 2);
        p += __shfl_xor(p, 4);
        float wg = __expf(p * scale);
        den += wg;
        float va, vb_, vc, vd;
        fp8_to_f4(vu, va, vb_, vc, vd);
        a0 = fmaf(wg, va, a0); a1 = fmaf(wg, vb_, a1); a2 = fmaf(wg, vc, a2); a3 = fmaf(wg, vd, a3);
    }
    den += __shfl_xor(den, 32);
    a0 += __shfl_xor(a0, 32); a1 += __shfl_xor(a1, 32);
    a2 += __shfl_xor(a2, 32); a3 += __shfl_xor(a3, 32);
    float inv = (den > 0.f) ? 1.f/den : 0.f;
    float o0 = bflo(sbv.x) + a0*inv;
    float o1 = bfhi(sbv.x) + a1*inv;
    float o2 = bflo(sbv.y) + a2*inv;
    float o3 = bfhi(sbv.y) + a3*inv;
    if (half == 0){
        float4 o; o.x = o0; o.y = o1; o.z = o2; o.w = o3;
        *(float4*)(h2 + (size_t)n*128 + l5*4) = o;
        float4 t; t.x = o0; t.y = o1; t.z = o2; t.w = o3;
        *(float4*)&sm[0][w][l5*4] = t;
    } else {
        float4 t; t.x = o0*o0; t.y = o1*o1; t.z = o2*o2; t.w = o3*o3;
        *(float4*)&sm[1][w][l5*4] = t;
    }
    __syncthreads();
    // fused bn2 stats -> hierarchical partial group (blockIdx & 63)
    {
        int t = threadIdx.x;
        int st = t >> 7, c = t & 127;
        float v = sm[st][0][c] + sm[st][1][c] + sm[st][2][c] + sm[st][3][c];
        atomicAdd(&part2[(blockIdx.x & 63)*256 + st*128 + c], v);
    }
}

// ---------------------------------------------------------------------------
// SAGE mean aggregation: CSR prefetch, 4 edges/half, fp8 gathers (4 B/lane)
// ---------------------------------------------------------------------------
__global__ __launch_bounds__(256) void sage_agg(const uchar_t* __restrict__ x28,
                                                const int* __restrict__ rs,
                                                const int* __restrict__ csr,
                                                ushort_t* __restrict__ nmeanb){
    int w = threadIdx.x >> 6, lane = threadIdx.x & 63;
    int n = blockIdx.x*4 + w;
    if (n >= NN) return;
    int half = lane >> 5, l5 = lane & 31;
    int e0 = rs[n*8], e1 = rs[n*8 + 8];
    int deg = e1 - e0;
    int idx = 0;
    if (lane < deg) idx = csr[e0 + lane];
    int dcap = min(deg, 64);
    int nt = (dcap + 7) >> 3;
    f32x2 A0 = {0.f,0.f}, A1 = {0.f,0.f};
    for (int t = 0; t < nt; ++t){
        int i2 = t*8 + half*4;
        int j0 = i2, j1 = i2+1, j2 = i2+2, j3 = i2+3;
        bool v0 = j0 < dcap, v1 = j1 < dcap, v2 = j2 < dcap, v3 = j3 < dcap;
        int s0 = __shfl(idx, j0 & 63); s0 = v0 ? s0 : 0;
        int s1 = __shfl(idx, j1 & 63); s1 = v1 ? s1 : 0;
        int s2 = __shfl(idx, j2 & 63); s2 = v2 ? s2 : 0;
        int s3 = __shfl(idx, j3 & 63); s3 = v3 ? s3 : 0;
        unsigned int u0 = *(const unsigned int*)(x28 + (size_t)s0*128 + l5*4);
        unsigned int u1 = *(const unsigned int*)(x28 + (size_t)s1*128 + l5*4);
        unsigned int u2 = *(const unsigned int*)(x28 + (size_t)s2*128 + l5*4);
        unsigned int u3 = *(const unsigned int*)(x28 + (size_t)s3*128 + l5*4);
        u0 = v0 ? u0 : 0u; u1 = v1 ? u1 : 0u;
        u2 = v2 ? u2 : 0u; u3 = v3 ? u3 : 0u;
        A0 += __builtin_amdgcn_cvt_pk_f32_fp8(u0, false);
        A1 += __builtin_amdgcn_cvt_pk_f32_fp8(u0, true);
        A0 += __builtin_amdgcn_cvt_pk_f32_fp8(u1, false);
        A1 += __builtin_amdgcn_cvt_pk_f32_fp8(u1, true);
        A0 += __builtin_amdgcn_cvt_pk_f32_fp8(u2, false);
        A1 += __builtin_amdgcn_cvt_pk_f32_fp8(u2, true);
        A0 += __builtin_amdgcn_cvt_pk_f32_fp8(u3, false);
        A1 += __builtin_amdgcn_cvt_pk_f32_fp8(u3, true);
    }
    for (int e = 64 + half; e < deg; e += 2){
        int s = csr[e0 + e];
        unsigned int u = *(const unsigned int*)(x28 + (size_t)s*128 + l5*4);
        A0 += __builtin_amdgcn_cvt_pk_f32_fp8(u, false);
        A1 += __builtin_amdgcn_cvt_pk_f32_fp8(u, true);
    }
    float a0 = A0.x, a1 = A0.y, a2 = A1.x, a3 = A1.y;
    a0 += __shfl_xor(a0, 32); a1 += __shfl_xor(a1, 32);
    a2 += __shfl_xor(a2, 32); a3 += __shfl_xor(a3, 32);
    if (half == 0){
        float inv = 1.f / fmaxf((float)deg, 1.f);
        ushort4 o;
        o.x = f2bf(a0*inv); o.y = f2bf(a1*inv); o.z = f2bf(a2*inv); o.w = f2bf(a3*inv);
        *(ushort4*)(nmeanb + (size_t)n*128 + l5*4) = o;
    }
}

// ---------------------------------------------------------------------------
extern "C" void kernel_launch(void* const* d_in, const int* in_sizes, int n_in,
                              void* d_out, int out_size, void* d_ws, size_t ws_size,
                              hipStream_t stream){
    const float* nf      = (const float*)d_in[0];
    const int*   ei      = (const int*)d_in[2];
    const int*   et      = (const int*)d_in[3];
    const float* rgcn_w  = (const float*)d_in[4];
    const float* root    = (const float*)d_in[5];
    const float* rbias   = (const float*)d_in[6];
    const float* bn1g    = (const float*)d_in[7];
    const float* bn1b    = (const float*)d_in[8];
    const float* wq      = (const float*)d_in[9];
    const float* bq      = (const float*)d_in[10];
    const float* wk      = (const float*)d_in[11];
    const float* bk      = (const float*)d_in[12];
    const float* wv      = (const float*)d_in[13];
    const float* bv      = (const float*)d_in[14];
    const float* wsk     = (const float*)d_in[15];
    const float* bsk     = (const float*)d_in[16];
    const float* bn2g    = (const float*)d_in[17];
    const float* bn2b    = (const float*)d_in[18];
    const float* wl      = (const float*)d_in[19];
    const float* bl      = (const float*)d_in[20];
    const float* wr      = (const float*)d_in[21];
    const float* bn3g    = (const float*)d_in[22];
    const float* bn3b    = (const float*)d_in[23];
    float* out = (float*)d_out;

    // ---- workspace carve (256B aligned) ----
    char* base = (char*)d_ws;
    size_t off = 0;
    auto take = [&](size_t bytes) -> char* {
        char* p = base + off;
        off += (bytes + 255) & ~(size_t)255;
        return p;
    };
    int*      deg    = (int*)take((size_t)NR*4);
    float*    bns    = (float*)take(1024*4);
    float*    part1  = (float*)take(32*128*4);              // bn1 partials (16 KB)
    float*    part2  = (float*)take(64*256*4);              // bn2 partials (64 KB)
    float*    part3  = (float*)take(4*64*4);                // bn3 partials (1 KB)
    char*     zend   = base + off;                     // zero [deg, zend) in one memset
    int*      rs     = (int*)take((size_t)(NR+1)*4);
    int*      tmp    = (int*)take((size_t)NR*4);
    int*      bsum   = (int*)take(1024*4);
    uint2*    sr     = (uint2*)take((size_t)NE*8);          // (seg, rank) per edge (6.4 MB)
    int*      csr    = (int*)take((size_t)NE*4);
    ushort_t* Wcat   = (ushort_t*)take(64*576*2);
    ushort_t* Wt2    = (ushort_t*)take(512*64*2);
    float*    bcat   = (float*)take(512*4);
    ushort_t* Wsage  = (ushort_t*)take(32*256*2);
    ushort_t* xb     = (ushort_t*)take((size_t)NN*64*2);
    uchar_t*  xb8    = (uchar_t*)take((size_t)NN*64);       // fp8 gather copy (3.2 MB)
    float*    h1pre  = (float*)take((size_t)NN*64*4);
    float*    h2     = (float*)take((size_t)NN*128*4);
    float*    x2r    = (float*)take((size_t)NN*32*4);
    ushort_t* sb     = (ushort_t*)take((size_t)NN*128*2);   // bf16 skip (12.8 MB)
    char*     bigA   = take((size_t)NN*512*2);              // 51.2 MB multi-use
    if (off > ws_size) return;

    // bigA aliases (byte offsets); lifetimes verified stage-by-stage:
    ushort_t* qb     = (ushort_t*)(bigA + (size_t)NN*128);       // gemm_qkvs -> attn (12.8 MB)
    uchar_t*  vb8    = (uchar_t*)(bigA + (size_t)NN*384);        // gemm_qkvs -> attn (6.4 MB)
    uchar_t*  kb8    = (uchar_t*)(bigA + (size_t)NN*640);        // gemm_qkvs -> attn (6.4 MB)
    ushort_t* x2b    = (ushort_t*)bigA;                          // bn_apply2 -> sage_gemm (12.8 MB)
    uchar_t*  x28    = (uchar_t*)(bigA + (size_t)NN*256);        // bn_apply2 -> sage_agg (6.4 MB)
    ushort_t* nmeanb = (ushort_t*)(bigA + (size_t)NN*512);       // sage_agg -> sage_gemm (12.8 MB)
    float*    h3     = (float*)(bigA + (size_t)NN*768);          // sage_gemm -> bn3 (6.4 MB)

    hipMemsetAsync(deg, 0, (size_t)(zend - (char*)deg), stream); // deg + bns + partials

    // ---- CSR build (edges-first 4x-batched atomic pass) + weight prep ----
    const int PREP_N = NE4 + NN*16 + 64*576 + 512*64 + 512 + 32*256;
    k_prep <<<(PREP_N+255)/256, 256, 0, stream>>>(nf, rgcn_w, root, wq, wk, wv, wsk,
                                                  bq, bk, bv, bsk, wl, wr,
                                                  ei, et, deg, sr,
                                                  xb, xb8, Wcat, Wt2, bcat, Wsage);
    k_scan1<<<NB2, SCAN_BS, 0, stream>>>(deg, tmp, bsum);
    k_scan2<<<1, 1024, 0, stream>>>(bsum);
    k_scan3<<<(NR+255)/256, 256, 0, stream>>>(tmp, bsum, rs);
    k_fill <<<(NE+255)/256, 256, 0, stream>>>(ei, sr, rs, csr);

    const int NB4 = (NN + 3) / 4;
    const int NBG = (NN + 63) / 64;

    // ---- stage 1: RGCN (fused agg + MFMA + bn1 partial stats) ----
    rgcn_fused<<<NN/16, 256, 0, stream>>>(xb, xb8, rs, csr, Wcat, rbias, h1pre, part1);

    // ---- stage 2: TransformerConv ----
    gemm_qkvs<<<NBG, 256, 0, stream>>>(h1pre, nf, part1, bn1g, bn1b,
                                       Wt2, bcat, qb, kb8, vb8, sb);
    attn_kernel<<<NB4, 256, 0, stream>>>(qb, kb8, vb8, sb, rs, csr, h2, part2);
    k_red2<<<1, 256, 0, stream>>>(part1, part2, bns);
    bn_apply2<<<(NN*128+255)/256, 256, 0, stream>>>(h2, h1pre, nf,
                                                    bn1g, bn1b, bns + 0, bns + 64,
                                                    bn2g, bn2b, bns + 128, bns + 256,
                                                    x2r, x2b, x28);

    // ---- stage 3: SAGE ----
    sage_agg<<<NB4, 256, 0, stream>>>(x28, rs, csr, nmeanb);
    sage_gemm<<<NBG, 256, 0, stream>>>(x2b, nmeanb, Wsage, bl, h3, part3);
    bn_apply3<<<(NN*32+255)/256, 256, 0, stream>>>(h3, x2r, bn3g, bn3b, part3, out);
}